// Round 1
// baseline (1465.975 us; speedup 1.0000x reference)
//
#include <hip/hip_runtime.h>
#include <hip/hip_bf16.h>
#include <cstdint>

// ---------------------------------------------------------------------------
// FullModel: hetero-GraphSAGE (2 layers) + 3 MLP heads, fp32 baseline.
// Structure:
//   1. l2norm rows of x_client / x_sku        -> concat_c[:,128:256], concat_s[:,128:256]
//   2. CSR build for both edge sets (hist/scan/scatter), no float atomics
//   3. mean-aggregate (gather, reg accumulate) -> concat_*[:,0:128]
//   4. GEMM1 (relu): [mean||x] @ Wcomb.T      -> h1_s, h1_c (h1_c into concat2[:,256:512])
//   5. layer-2 mean-aggregate h1_s over sc CSR -> concat2[:,0:256]
//   6. GEMM2: concat2 @ W2comb.T              -> user_emb (d_out)
//   7. fused head hidden GEMM (relu, 384 cols), then churn dot / cat / sku GEMMs (sigmoid)
// Weight folding: lin_r and residual Wlin both multiply x_dst -> summed once on device.
// ---------------------------------------------------------------------------

__device__ __forceinline__ float waveReduceSum(float v) {
  #pragma unroll
  for (int s = 32; s > 0; s >>= 1) v += __shfl_xor(v, s, 64);
  return v;
}

// ---- l2 normalize 128-wide rows into a strided destination ----
__global__ void k_l2norm(const float* __restrict__ x,
                         float* __restrict__ out, int out_stride, int out_off, int n) {
  int wid = (blockIdx.x * blockDim.x + threadIdx.x) >> 6;
  int lane = threadIdx.x & 63;
  if (wid >= n) return;
  const float2 v = *(const float2*)&x[(size_t)wid * 128 + lane * 2];
  float ss = waveReduceSum(v.x * v.x + v.y * v.y);
  float scale = 1.0f / fmaxf(sqrtf(ss), 1e-12f);
  float* o = &out[(size_t)wid * out_stride + out_off + lane * 2];
  o[0] = v.x * scale;
  o[1] = v.y * scale;
}

// ---- histogram of dst indices ----
__global__ void k_hist(const int* __restrict__ dst, int* __restrict__ cnt, int E) {
  int i = blockIdx.x * blockDim.x + threadIdx.x;
  if (i < E) atomicAdd(&cnt[dst[i]], 1);
}

// ---- 3-kernel exclusive scan (chunks of 2048 = 256 thr x 8) ----
__global__ void k_scan1(const int* __restrict__ in, int* __restrict__ out,
                        int* __restrict__ partials, int n) {
  __shared__ int sd[256];
  const int tid = threadIdx.x;
  const int base = blockIdx.x * 2048 + tid * 8;
  int v[8];
  int tsum = 0;
  #pragma unroll
  for (int u = 0; u < 8; ++u) {
    int idx = base + u;
    int t = (idx < n) ? in[idx] : 0;
    v[u] = tsum; tsum += t;
  }
  sd[tid] = tsum;
  __syncthreads();
  for (int offp = 1; offp < 256; offp <<= 1) {
    int t = (tid >= offp) ? sd[tid - offp] : 0;
    __syncthreads();
    sd[tid] += t;
    __syncthreads();
  }
  int texcl = (tid == 0) ? 0 : sd[tid - 1];
  if (tid == 255) partials[blockIdx.x] = sd[255];
  #pragma unroll
  for (int u = 0; u < 8; ++u) {
    int idx = base + u;
    if (idx < n) out[idx] = v[u] + texcl;
  }
}

__global__ void k_scan2(int* __restrict__ partials, int nb) {
  __shared__ int sd[256];
  const int tid = threadIdx.x;
  int v = (tid < nb) ? partials[tid] : 0;
  sd[tid] = v;
  __syncthreads();
  for (int offp = 1; offp < 256; offp <<= 1) {
    int t = (tid >= offp) ? sd[tid - offp] : 0;
    __syncthreads();
    sd[tid] += t;
    __syncthreads();
  }
  if (tid < nb) partials[tid] = (tid == 0) ? 0 : sd[tid - 1];
}

__global__ void k_scan3(int* __restrict__ out, const int* __restrict__ partials, int n) {
  int add = partials[blockIdx.x];
  int base = blockIdx.x * 2048 + threadIdx.x * 8;
  #pragma unroll
  for (int u = 0; u < 8; ++u) {
    int idx = base + u;
    if (idx < n) out[idx] += add;
  }
}

__global__ void k_settail(int* __restrict__ off, int n, int val) { off[n] = val; }

// ---- scatter edges into CSR buckets ----
__global__ void k_scatter(const int* __restrict__ src, const int* __restrict__ dst,
                          const int* __restrict__ off, int* __restrict__ cur,
                          int* __restrict__ lst, int E) {
  int i = blockIdx.x * blockDim.x + threadIdx.x;
  if (i < E) {
    int d = dst[i];
    int p = atomicAdd(&cur[d], 1);
    lst[off[d] + p] = src[i];
  }
}

// ---- mean-aggregate 128-wide features, one wave per destination ----
__global__ void k_agg_mean128(const float* __restrict__ feat, int fstride, int foff,
                              const int* __restrict__ off, const int* __restrict__ lst,
                              float* __restrict__ out, int ostride, int ooff, int n) {
  int wid = (blockIdx.x * blockDim.x + threadIdx.x) >> 6;
  int lane = threadIdx.x & 63;
  if (wid >= n) return;
  int s = off[wid], e = off[wid + 1];
  float ax = 0.f, ay = 0.f;
  for (int i = s; i < e; ++i) {
    int sidx = lst[i];
    const float2 v = *(const float2*)&feat[(size_t)sidx * fstride + foff + lane * 2];
    ax += v.x; ay += v.y;
  }
  float inv = 1.0f / (float)((e - s) > 0 ? (e - s) : 1);
  float* o = &out[(size_t)wid * ostride + ooff + lane * 2];
  o[0] = ax * inv;
  o[1] = ay * inv;
}

// ---- mean-aggregate 256-wide features, one wave per destination ----
__global__ void k_agg_mean256(const float* __restrict__ feat, int fstride, int foff,
                              const int* __restrict__ off, const int* __restrict__ lst,
                              float* __restrict__ out, int ostride, int ooff, int n) {
  int wid = (blockIdx.x * blockDim.x + threadIdx.x) >> 6;
  int lane = threadIdx.x & 63;
  if (wid >= n) return;
  int s = off[wid], e = off[wid + 1];
  float4 acc = make_float4(0.f, 0.f, 0.f, 0.f);
  for (int i = s; i < e; ++i) {
    int sidx = lst[i];
    const float4 v = *(const float4*)&feat[(size_t)sidx * fstride + foff + lane * 4];
    acc.x += v.x; acc.y += v.y; acc.z += v.z; acc.w += v.w;
  }
  float inv = 1.0f / (float)((e - s) > 0 ? (e - s) : 1);
  float* o = &out[(size_t)wid * ostride + ooff + lane * 4];
  o[0] = acc.x * inv; o[1] = acc.y * inv; o[2] = acc.z * inv; o[3] = acc.w * inv;
}

// ---- weight folding: wc[n][k] = k<Kh ? wl[n][k] : wr[n][k-Kh]+wlin[n][k-Kh] ----
__global__ void k_prep_comb(const float* __restrict__ wl, const float* __restrict__ wr,
                            const float* __restrict__ wlin,
                            const float* __restrict__ bl, const float* __restrict__ blin,
                            float* __restrict__ wc, float* __restrict__ bc,
                            int N, int Kh) {
  int i = blockIdx.x * blockDim.x + threadIdx.x;
  int tot = N * 2 * Kh;
  if (i < tot) {
    int n = i / (2 * Kh), k = i % (2 * Kh);
    wc[i] = (k < Kh) ? wl[n * Kh + k] : (wr[n * Kh + k - Kh] + wlin[n * Kh + k - Kh]);
  }
  if (i < N) bc[i] = bl[i] + blin[i];
}

// ---- fold the 3 head first-layers into one 384x128 weight ----
__global__ void k_prep_heads(const float* __restrict__ w1, const float* __restrict__ b1,
                             const float* __restrict__ w2, const float* __restrict__ b2,
                             const float* __restrict__ w3, const float* __restrict__ b3,
                             float* __restrict__ wc, float* __restrict__ bc) {
  int i = blockIdx.x * blockDim.x + threadIdx.x;
  if (i < 384 * 128) {
    int n = i >> 7, k = i & 127;
    const float* w = (n < 128) ? w1 : ((n < 256) ? w2 : w3);
    wc[i] = w[(n & 127) * 128 + k];
  }
  if (i < 384) bc[i] = (i < 128) ? b1[i] : ((i < 256) ? b2[i - 128] : b3[i - 256]);
}

// ---- fp32 tiled GEMM: C[M,N] = act(A[M,K] @ W[N,K]^T + bias) ----
// ACT: 0 none, 1 relu, 2 sigmoid
template <int ACT>
__global__ __launch_bounds__(256) void k_gemm(
    const float* __restrict__ A, int lda,
    const float* __restrict__ W, int ldw,
    const float* __restrict__ bias,
    float* __restrict__ C, int ldc,
    int M, int N, int K) {
  __shared__ float As[16][64];
  __shared__ float Bs[16][64];
  const int bm = blockIdx.y * 64;
  const int bn = blockIdx.x * 64;
  const int tid = threadIdx.x;
  const int tx = tid & 15;
  const int ty = tid >> 4;
  const int lr = tid >> 2;          // tile row to load (0..63)
  const int lc = (tid & 3) << 2;    // k offset within BK (0,4,8,12)
  const bool arow_ok = (bm + lr) < M;
  const bool wrow_ok = (bn + lr) < N;
  const float* Aptr = A + (size_t)(bm + lr) * lda + lc;
  const float* Wptr = W + (size_t)(bn + lr) * ldw + lc;
  float acc[4][4] = {};
  for (int k0 = 0; k0 < K; k0 += 16) {
    float4 av = arow_ok ? *(const float4*)(Aptr + k0) : make_float4(0, 0, 0, 0);
    float4 wv = wrow_ok ? *(const float4*)(Wptr + k0) : make_float4(0, 0, 0, 0);
    __syncthreads();
    As[lc + 0][lr] = av.x; As[lc + 1][lr] = av.y; As[lc + 2][lr] = av.z; As[lc + 3][lr] = av.w;
    Bs[lc + 0][lr] = wv.x; Bs[lc + 1][lr] = wv.y; Bs[lc + 2][lr] = wv.z; Bs[lc + 3][lr] = wv.w;
    __syncthreads();
    #pragma unroll
    for (int k = 0; k < 16; ++k) {
      const float4 a4 = *(const float4*)&As[k][ty << 2];
      const float4 b4 = *(const float4*)&Bs[k][tx << 2];
      const float ar[4] = {a4.x, a4.y, a4.z, a4.w};
      const float br[4] = {b4.x, b4.y, b4.z, b4.w};
      #pragma unroll
      for (int i = 0; i < 4; ++i)
        #pragma unroll
        for (int j = 0; j < 4; ++j)
          acc[i][j] += ar[i] * br[j];
    }
  }
  #pragma unroll
  for (int i = 0; i < 4; ++i) {
    int row = bm + (ty << 2) + i;
    if (row >= M) continue;
    #pragma unroll
    for (int j = 0; j < 4; ++j) {
      int col = bn + (tx << 2) + j;
      if (col >= N) continue;
      float v = acc[i][j] + bias[col];
      if (ACT == 1) v = fmaxf(v, 0.0f);
      else if (ACT == 2) v = 1.0f / (1.0f + __expf(-v));
      C[(size_t)row * ldc + col] = v;
    }
  }
}

// ---- churn head: N=1 output, one wave per row ----
__global__ void k_churn(const float* __restrict__ hid, int ld,
                        const float* __restrict__ w, const float* __restrict__ b,
                        float* __restrict__ out, int n) {
  int wid = (blockIdx.x * blockDim.x + threadIdx.x) >> 6;
  int lane = threadIdx.x & 63;
  if (wid >= n) return;
  const float2 h = *(const float2*)&hid[(size_t)wid * ld + lane * 2];
  const float2 ww = *(const float2*)&w[lane * 2];
  float sum = waveReduceSum(h.x * ww.x + h.y * ww.y);
  if (lane == 0) out[wid] = 1.0f / (1.0f + __expf(-(sum + b[0])));
}

extern "C" void kernel_launch(void* const* d_in, const int* in_sizes, int n_in,
                              void* d_out, int out_size, void* d_ws, size_t ws_size,
                              hipStream_t stream) {
  const float* x_client = (const float*)d_in[0];
  const float* x_sku    = (const float*)d_in[1];
  const int* cs_src = (const int*)d_in[2];
  const int* cs_dst = (const int*)d_in[3];
  const int* sc_src = (const int*)d_in[4];
  const int* sc_dst = (const int*)d_in[5];
  const float* W1l_cs = (const float*)d_in[6];
  const float* b1_cs  = (const float*)d_in[7];
  const float* W1r_cs = (const float*)d_in[8];
  const float* W1l_sc = (const float*)d_in[9];
  const float* b1_sc  = (const float*)d_in[10];
  const float* W1r_sc = (const float*)d_in[11];
  const float* Wlin1_c = (const float*)d_in[12];
  const float* blin1_c = (const float*)d_in[13];
  const float* Wlin1_s = (const float*)d_in[14];
  const float* blin1_s = (const float*)d_in[15];
  // d_in[16..18] (W2l_cs, b2_cs, W2r_cs) and d_in[24..25] (Wlin2_s, blin2_s)
  // are dead code: layer 2 only produces client output.
  const float* W2l_sc = (const float*)d_in[19];
  const float* b2_sc  = (const float*)d_in[20];
  const float* W2r_sc = (const float*)d_in[21];
  const float* Wlin2_c = (const float*)d_in[22];
  const float* blin2_c = (const float*)d_in[23];
  const float* Wch1 = (const float*)d_in[26];
  const float* bch1 = (const float*)d_in[27];
  const float* Wch2 = (const float*)d_in[28];
  const float* bch2 = (const float*)d_in[29];
  const float* Wcat1 = (const float*)d_in[30];
  const float* bcat1 = (const float*)d_in[31];
  const float* Wcat2 = (const float*)d_in[32];
  const float* bcat2 = (const float*)d_in[33];
  const float* Wsk1 = (const float*)d_in[34];
  const float* bsk1 = (const float*)d_in[35];
  const float* Wsk2 = (const float*)d_in[36];
  const float* bsk2 = (const float*)d_in[37];

  const int D = 128;
  const int Nc = in_sizes[0] / D;
  const int Ns = in_sizes[1] / D;
  const int E  = in_sizes[2];
  const int NCAT = in_sizes[33];
  const int NSKU = in_sizes[37];

  // ---- workspace layout ----
  char* wsb = (char*)d_ws;
  size_t o = 0;
  auto alloc = [&](size_t bytes) -> char* {
    char* p = wsb + o;
    o = (o + bytes + 255) & ~(size_t)255;
    return p;
  };
  float* concat_s = (float*)alloc((size_t)Ns * 256 * 4);  // [mean_cs || xs_norm]
  float* concat_c = (float*)alloc((size_t)Nc * 256 * 4);  // [mean_sc || xc_norm]
  float* h1_s     = (float*)alloc((size_t)Ns * 256 * 4);
  float* big      = (float*)alloc((size_t)Nc * 512 * 4);  // concat2_c, then reused as hidden
  float* wc1s = (float*)alloc(256 * 256 * 4);
  float* bc1s = (float*)alloc(256 * 4);
  float* wc1c = (float*)alloc(256 * 256 * 4);
  float* bc1c = (float*)alloc(256 * 4);
  float* wc2c = (float*)alloc(128 * 512 * 4);
  float* bc2c = (float*)alloc(128 * 4);
  float* whh  = (float*)alloc(384 * 128 * 4);
  float* bhh  = (float*)alloc(384 * 4);
  int* cs_off = (int*)alloc((size_t)(Ns + 1) * 4);
  int* sc_off = (int*)alloc((size_t)(Nc + 1) * 4);
  int* zbase  = (int*)alloc((size_t)(2 * Ns + 2 * Nc) * 4);
  int* cs_cnt = zbase;
  int* sc_cnt = cs_cnt + Ns;
  int* cs_cur = sc_cnt + Nc;
  int* sc_cur = cs_cur + Ns;
  int* cs_lst = (int*)alloc((size_t)E * 4);
  int* sc_lst = (int*)alloc((size_t)E * 4);
  int* partials = (int*)alloc(1024 * 4);

  float* out_churn = (float*)d_out;
  float* out_cat = out_churn + (size_t)Nc;
  float* out_sku = out_cat + (size_t)Nc * NCAT;
  float* out_emb = out_sku + (size_t)Nc * NSKU;

  // ---- zero histogram/cursor scratch (re-done every call: replay-safe) ----
  hipMemsetAsync(zbase, 0, (size_t)(2 * Ns + 2 * Nc) * 4, stream);

  // ---- weight folding ----
  k_prep_comb<<<(256 * 256 + 255) / 256, 256, 0, stream>>>(
      W1l_cs, W1r_cs, Wlin1_s, b1_cs, blin1_s, wc1s, bc1s, 256, 128);
  k_prep_comb<<<(256 * 256 + 255) / 256, 256, 0, stream>>>(
      W1l_sc, W1r_sc, Wlin1_c, b1_sc, blin1_c, wc1c, bc1c, 256, 128);
  k_prep_comb<<<(128 * 512 + 255) / 256, 256, 0, stream>>>(
      W2l_sc, W2r_sc, Wlin2_c, b2_sc, blin2_c, wc2c, bc2c, 128, 256);
  k_prep_heads<<<(384 * 128 + 255) / 256, 256, 0, stream>>>(
      Wch1, bch1, Wcat1, bcat1, Wsk1, bsk1, whh, bhh);

  // ---- l2norm into right half of concat buffers ----
  k_l2norm<<<(Nc + 3) / 4, 256, 0, stream>>>(x_client, concat_c, 256, 128, Nc);
  k_l2norm<<<(Ns + 3) / 4, 256, 0, stream>>>(x_sku, concat_s, 256, 128, Ns);

  // ---- CSR build: cs (dst=sku) and sc (dst=client) ----
  k_hist<<<(E + 255) / 256, 256, 0, stream>>>(cs_dst, cs_cnt, E);
  k_hist<<<(E + 255) / 256, 256, 0, stream>>>(sc_dst, sc_cnt, E);

  int nb_cs = (Ns + 2047) / 2048;
  k_scan1<<<nb_cs, 256, 0, stream>>>(cs_cnt, cs_off, partials, Ns);
  k_scan2<<<1, 256, 0, stream>>>(partials, nb_cs);
  k_scan3<<<nb_cs, 256, 0, stream>>>(cs_off, partials, Ns);
  k_settail<<<1, 1, 0, stream>>>(cs_off, Ns, E);

  int nb_sc = (Nc + 2047) / 2048;
  k_scan1<<<nb_sc, 256, 0, stream>>>(sc_cnt, sc_off, partials, Nc);
  k_scan2<<<1, 256, 0, stream>>>(partials, nb_sc);
  k_scan3<<<nb_sc, 256, 0, stream>>>(sc_off, partials, Nc);
  k_settail<<<1, 1, 0, stream>>>(sc_off, Nc, E);

  k_scatter<<<(E + 255) / 256, 256, 0, stream>>>(cs_src, cs_dst, cs_off, cs_cur, cs_lst, E);
  k_scatter<<<(E + 255) / 256, 256, 0, stream>>>(sc_src, sc_dst, sc_off, sc_cur, sc_lst, E);

  // ---- layer-1 mean aggregation ----
  k_agg_mean128<<<(Ns + 3) / 4, 256, 0, stream>>>(concat_c, 256, 128, cs_off, cs_lst,
                                                  concat_s, 256, 0, Ns);
  k_agg_mean128<<<(Nc + 3) / 4, 256, 0, stream>>>(concat_s, 256, 128, sc_off, sc_lst,
                                                  concat_c, 256, 0, Nc);

  // ---- layer-1 GEMMs (relu) ----
  {
    dim3 g((256 + 63) / 64, (Ns + 63) / 64);
    k_gemm<1><<<g, 256, 0, stream>>>(concat_s, 256, wc1s, 256, bc1s, h1_s, 256, Ns, 256, 256);
  }
  {
    dim3 g((256 + 63) / 64, (Nc + 63) / 64);
    k_gemm<1><<<g, 256, 0, stream>>>(concat_c, 256, wc1c, 256, bc1c, big + 256, 512, Nc, 256, 256);
  }

  // ---- layer-2 aggregation of h1_s over sc CSR ----
  k_agg_mean256<<<(Nc + 3) / 4, 256, 0, stream>>>(h1_s, 256, 0, sc_off, sc_lst, big, 512, 0, Nc);

  // ---- layer-2 GEMM -> user_emb (no act) ----
  {
    dim3 g((128 + 63) / 64, (Nc + 63) / 64);
    k_gemm<0><<<g, 256, 0, stream>>>(big, 512, wc2c, 512, bc2c, out_emb, 128, Nc, 128, 512);
  }

  // ---- fused head hidden (relu): 384 cols, reuse `big` as hidden ----
  float* hidden = big;
  {
    dim3 g((384 + 63) / 64, (Nc + 63) / 64);
    k_gemm<1><<<g, 256, 0, stream>>>(out_emb, 128, whh, 128, bhh, hidden, 384, Nc, 384, 128);
  }

  // ---- heads ----
  k_churn<<<(Nc + 3) / 4, 256, 0, stream>>>(hidden, 384, Wch2, bch2, out_churn, Nc);
  {
    dim3 g((NCAT + 63) / 64, (Nc + 63) / 64);
    k_gemm<2><<<g, 256, 0, stream>>>(hidden + 128, 384, Wcat2, 128, bcat2, out_cat, NCAT,
                                     Nc, NCAT, 128);
  }
  {
    dim3 g((NSKU + 63) / 64, (Nc + 63) / 64);
    k_gemm<2><<<g, 256, 0, stream>>>(hidden + 256, 384, Wsk2, 128, bsk2, out_sku, NSKU,
                                     Nc, NSKU, 128);
  }
}

// Round 2
// 822.709 us; speedup vs baseline: 1.7819x; 1.7819x over previous
//
#include <hip/hip_runtime.h>
#include <hip/hip_bf16.h>
#include <cstdint>

// ---------------------------------------------------------------------------
// FullModel: hetero-GraphSAGE (2 layers) + 3 MLP heads.
// R2: all GEMMs moved to bf16 MFMA (16x16x32, fp32 accumulate), intermediates
// stored bf16, 128x128 tiles staged via global_load_lds(16B) with XOR-swizzled
// LDS (pre-swizzled global source), XCD-aware block swizzle, fused epilogues.
// Graph part (CSR build + mean aggregation) unchanged except bf16 features.
// ---------------------------------------------------------------------------

typedef __attribute__((ext_vector_type(8))) short bf16x8;
typedef __attribute__((ext_vector_type(4))) float f32x4;

__device__ __forceinline__ float b2f(unsigned short u) {
  return __uint_as_float(((unsigned)u) << 16);
}
__device__ __forceinline__ unsigned short f2b(float f) {
  unsigned u = __float_as_uint(f);
  return (unsigned short)((u + 0x7FFFu + ((u >> 16) & 1u)) >> 16);
}

__device__ __forceinline__ float waveReduceSum(float v) {
  #pragma unroll
  for (int s = 32; s > 0; s >>= 1) v += __shfl_xor(v, s, 64);
  return v;
}

__device__ __forceinline__ void gload16(const void* g, void* l) {
  __builtin_amdgcn_global_load_lds(
      (const __attribute__((address_space(1))) unsigned int*)g,
      (__attribute__((address_space(3))) unsigned int*)l, 16, 0, 0);
}

// ---- l2 normalize 128-wide fp32 rows -> strided bf16 destination ----
__global__ void k_l2norm(const float* __restrict__ x,
                         unsigned short* __restrict__ out, int ostride, int ooff, int n) {
  int wid = (blockIdx.x * blockDim.x + threadIdx.x) >> 6;
  int lane = threadIdx.x & 63;
  if (wid >= n) return;
  const float2 v = *(const float2*)&x[(size_t)wid * 128 + lane * 2];
  float ss = waveReduceSum(v.x * v.x + v.y * v.y);
  float scale = 1.0f / fmaxf(sqrtf(ss), 1e-12f);
  unsigned short* o = &out[(size_t)wid * ostride + ooff + lane * 2];
  o[0] = f2b(v.x * scale);
  o[1] = f2b(v.y * scale);
}

// ---- histogram of dst indices ----
__global__ void k_hist(const int* __restrict__ dst, int* __restrict__ cnt, int E) {
  int i = blockIdx.x * blockDim.x + threadIdx.x;
  if (i < E) atomicAdd(&cnt[dst[i]], 1);
}

// ---- 3-kernel exclusive scan (chunks of 2048 = 256 thr x 8) ----
__global__ void k_scan1(const int* __restrict__ in, int* __restrict__ out,
                        int* __restrict__ partials, int n) {
  __shared__ int sd[256];
  const int tid = threadIdx.x;
  const int base = blockIdx.x * 2048 + tid * 8;
  int v[8];
  int tsum = 0;
  #pragma unroll
  for (int u = 0; u < 8; ++u) {
    int idx = base + u;
    int t = (idx < n) ? in[idx] : 0;
    v[u] = tsum; tsum += t;
  }
  sd[tid] = tsum;
  __syncthreads();
  for (int offp = 1; offp < 256; offp <<= 1) {
    int t = (tid >= offp) ? sd[tid - offp] : 0;
    __syncthreads();
    sd[tid] += t;
    __syncthreads();
  }
  int texcl = (tid == 0) ? 0 : sd[tid - 1];
  if (tid == 255) partials[blockIdx.x] = sd[255];
  #pragma unroll
  for (int u = 0; u < 8; ++u) {
    int idx = base + u;
    if (idx < n) out[idx] = v[u] + texcl;
  }
}

__global__ void k_scan2(int* __restrict__ partials, int nb) {
  __shared__ int sd[256];
  const int tid = threadIdx.x;
  int v = (tid < nb) ? partials[tid] : 0;
  sd[tid] = v;
  __syncthreads();
  for (int offp = 1; offp < 256; offp <<= 1) {
    int t = (tid >= offp) ? sd[tid - offp] : 0;
    __syncthreads();
    sd[tid] += t;
    __syncthreads();
  }
  if (tid < nb) partials[tid] = (tid == 0) ? 0 : sd[tid - 1];
}

__global__ void k_scan3(int* __restrict__ out, const int* __restrict__ partials, int n) {
  int add = partials[blockIdx.x];
  int base = blockIdx.x * 2048 + threadIdx.x * 8;
  #pragma unroll
  for (int u = 0; u < 8; ++u) {
    int idx = base + u;
    if (idx < n) out[idx] += add;
  }
}

__global__ void k_settail(int* __restrict__ off, int n, int val) { off[n] = val; }

// ---- scatter edges into CSR buckets ----
__global__ void k_scatter(const int* __restrict__ src, const int* __restrict__ dst,
                          const int* __restrict__ off, int* __restrict__ cur,
                          int* __restrict__ lst, int E) {
  int i = blockIdx.x * blockDim.x + threadIdx.x;
  if (i < E) {
    int d = dst[i];
    int p = atomicAdd(&cur[d], 1);
    lst[off[d] + p] = src[i];
  }
}

// ---- mean-aggregate 128-wide bf16 features, one wave per destination ----
__global__ void k_agg_mean128(const unsigned short* __restrict__ feat, int fstride, int foff,
                              const int* __restrict__ off, const int* __restrict__ lst,
                              unsigned short* __restrict__ out, int ostride, int ooff, int n) {
  int wid = (blockIdx.x * blockDim.x + threadIdx.x) >> 6;
  int lane = threadIdx.x & 63;
  if (wid >= n) return;
  int s = off[wid], e = off[wid + 1];
  float ax = 0.f, ay = 0.f;
  for (int i = s; i < e; ++i) {
    int sidx = lst[i];
    unsigned v = *(const unsigned*)&feat[(size_t)sidx * fstride + foff + lane * 2];
    ax += b2f((unsigned short)(v & 0xFFFF));
    ay += b2f((unsigned short)(v >> 16));
  }
  float inv = 1.0f / (float)((e - s) > 0 ? (e - s) : 1);
  unsigned short* o = &out[(size_t)wid * ostride + ooff + lane * 2];
  o[0] = f2b(ax * inv);
  o[1] = f2b(ay * inv);
}

// ---- mean-aggregate 256-wide bf16 features, one wave per destination ----
__global__ void k_agg_mean256(const unsigned short* __restrict__ feat, int fstride, int foff,
                              const int* __restrict__ off, const int* __restrict__ lst,
                              unsigned short* __restrict__ out, int ostride, int ooff, int n) {
  int wid = (blockIdx.x * blockDim.x + threadIdx.x) >> 6;
  int lane = threadIdx.x & 63;
  if (wid >= n) return;
  int s = off[wid], e = off[wid + 1];
  float a0 = 0.f, a1 = 0.f, a2 = 0.f, a3 = 0.f;
  for (int i = s; i < e; ++i) {
    int sidx = lst[i];
    uint2 v = *(const uint2*)&feat[(size_t)sidx * fstride + foff + lane * 4];
    a0 += b2f((unsigned short)(v.x & 0xFFFF));
    a1 += b2f((unsigned short)(v.x >> 16));
    a2 += b2f((unsigned short)(v.y & 0xFFFF));
    a3 += b2f((unsigned short)(v.y >> 16));
  }
  float inv = 1.0f / (float)((e - s) > 0 ? (e - s) : 1);
  unsigned short* o = &out[(size_t)wid * ostride + ooff + lane * 4];
  o[0] = f2b(a0 * inv); o[1] = f2b(a1 * inv); o[2] = f2b(a2 * inv); o[3] = f2b(a3 * inv);
}

// ---- weight folding: wc[n][k] = k<Kh ? wl[n][k] : wr[n][k-Kh]+wlin[n][k-Kh] (bf16) ----
__global__ void k_prep_comb(const float* __restrict__ wl, const float* __restrict__ wr,
                            const float* __restrict__ wlin,
                            const float* __restrict__ bl, const float* __restrict__ blin,
                            unsigned short* __restrict__ wc, float* __restrict__ bc,
                            int N, int Kh) {
  int i = blockIdx.x * blockDim.x + threadIdx.x;
  int tot = N * 2 * Kh;
  if (i < tot) {
    int n = i / (2 * Kh), k = i % (2 * Kh);
    float v = (k < Kh) ? wl[n * Kh + k] : (wr[n * Kh + k - Kh] + wlin[n * Kh + k - Kh]);
    wc[i] = f2b(v);
  }
  if (i < N) bc[i] = bl[i] + blin[i];
}

// ---- fold the 3 head first-layers into one 384x128 bf16 weight ----
__global__ void k_prep_heads(const float* __restrict__ w1, const float* __restrict__ b1,
                             const float* __restrict__ w2, const float* __restrict__ b2,
                             const float* __restrict__ w3, const float* __restrict__ b3,
                             unsigned short* __restrict__ wc, float* __restrict__ bc) {
  int i = blockIdx.x * blockDim.x + threadIdx.x;
  if (i < 384 * 128) {
    int n = i >> 7, k = i & 127;
    const float* w = (n < 128) ? w1 : ((n < 256) ? w2 : w3);
    wc[i] = f2b(w[(n & 127) * 128 + k]);
  }
  if (i < 384) bc[i] = (i < 128) ? b1[i] : ((i < 256) ? b2[i - 128] : b3[i - 256]);
}

// ---- cast fp32 [N][K] -> bf16 [Npad][K] with zero padding ----
__global__ void k_cast_pad(const float* __restrict__ w, unsigned short* __restrict__ out,
                           int N, int Npad, int K) {
  int i = blockIdx.x * blockDim.x + threadIdx.x;
  if (i < Npad * K) {
    int n = i / K;
    out[i] = (n < N) ? f2b(w[i]) : (unsigned short)0;
  }
}

// ---- bf16 MFMA GEMM: C[M,N] = act(A[M,K] @ W[N,K]^T + bias) ----
// 128x128 tile, 4 waves x 64x64, BK=32, global_load_lds staging with XOR
// swizzle (source-side pre-swizzle + read-side swizzle, G21).
// ACT: 0 none, 1 relu, 2 sigmoid.  OUTMODE: 0 f32, 1 bf16, 2 both.
// Requires: M-tiles/N-tiles cover padded allocations of A and W; K % 32 == 0.
template <int ACT, int OUTMODE>
__global__ __launch_bounds__(256) void k_gemm_mfma(
    const unsigned short* __restrict__ A, int lda,
    const unsigned short* __restrict__ W, int ldw,
    const float* __restrict__ bias,
    float* __restrict__ Cf, int ldcf,
    unsigned short* __restrict__ Cb, int ldcb,
    int M, int N, int K, int nt_n) {
  __shared__ __align__(16) unsigned short As[4096];  // [128][32] bf16, swizzled
  __shared__ __align__(16) unsigned short Bs[4096];

  // bijective XCD-aware swizzle (m204), n-fastest within each XCD chunk
  const int nwg = gridDim.x;
  const int orig = blockIdx.x;
  const int q8 = nwg >> 3, r8 = nwg & 7;
  const int xcd = orig & 7, cidx = orig >> 3;
  const int wg = (xcd < r8 ? xcd * (q8 + 1) : r8 * (q8 + 1) + (xcd - r8) * q8) + cidx;
  const int bm = (wg / nt_n) * 128;
  const int bn = (wg % nt_n) * 128;

  const int tid = threadIdx.x;
  const int lane = tid & 63;
  const int wave = tid >> 6;
  const int wm = (wave >> 1) << 6;   // 0 or 64
  const int wn = (wave & 1) << 6;    // 0 or 64
  const int l15 = lane & 15;
  const int l4 = lane >> 4;
  const int srd = l4 ^ (l15 & 3);    // read-side swizzled 16B slot

  f32x4 acc[4][4] = {};

  // staging geometry: slot p = wave*128 + j*64 + lane covers LDS 16B-slot p
  // (linear dest); source pre-swizzled so slot s_phys holds k-group s_phys^(r&3)
  const int sA0 = (wave * 128) * 8;      // ushort index of wave's j=0 LDS base
  const int sA1 = (wave * 128 + 64) * 8;

  for (int k0 = 0; k0 < K; k0 += 32) {
    #pragma unroll
    for (int j = 0; j < 2; ++j) {
      int p = wave * 128 + j * 64 + lane;
      int rr = p >> 2;
      int sl = (p & 3) ^ (rr & 3);
      const unsigned short* ga = A + (size_t)(bm + rr) * lda + k0 + (sl << 3);
      const unsigned short* gb = W + (size_t)(bn + rr) * ldw + k0 + (sl << 3);
      gload16(ga, (void*)&As[j == 0 ? sA0 : sA1]);
      gload16(gb, (void*)&Bs[j == 0 ? sA0 : sA1]);
    }
    __syncthreads();  // drains vmcnt(0): staged data visible
    bf16x8 af[4], bfr[4];
    #pragma unroll
    for (int i = 0; i < 4; ++i) {
      int ra = wm + i * 16 + l15;
      af[i] = *(const bf16x8*)&As[ra * 32 + (srd << 3)];
      int rb = wn + i * 16 + l15;
      bfr[i] = *(const bf16x8*)&Bs[rb * 32 + (srd << 3)];
    }
    #pragma unroll
    for (int i = 0; i < 4; ++i)
      #pragma unroll
      for (int j = 0; j < 4; ++j)
        acc[i][j] = __builtin_amdgcn_mfma_f32_16x16x32_bf16(af[i], bfr[j], acc[i][j], 0, 0, 0);
    __syncthreads();  // protect LDS for next iteration's staging
  }

  // epilogue: lane holds C[row=(l>>4)*4+q][col=l&15] per 16x16 fragment
  #pragma unroll
  for (int j = 0; j < 4; ++j) {
    int col = bn + wn + j * 16 + l15;
    float bj = (col < N) ? bias[col] : 0.0f;
    #pragma unroll
    for (int i = 0; i < 4; ++i) {
      int row0 = bm + wm + i * 16 + (l4 << 2);
      #pragma unroll
      for (int q = 0; q < 4; ++q) {
        int row = row0 + q;
        if (row < M && col < N) {
          float v = acc[i][j][q] + bj;
          if (ACT == 1) v = fmaxf(v, 0.0f);
          if (ACT == 2) v = 1.0f / (1.0f + __expf(-v));
          if (OUTMODE == 0 || OUTMODE == 2) Cf[(size_t)row * ldcf + col] = v;
          if (OUTMODE == 1 || OUTMODE == 2) Cb[(size_t)row * ldcb + col] = f2b(v);
        }
      }
    }
  }
}

// ---- churn head: dot(hidden[:,0:128], w) + b -> sigmoid, one wave per row ----
__global__ void k_churn(const unsigned short* __restrict__ hid, int ld,
                        const float* __restrict__ w, const float* __restrict__ b,
                        float* __restrict__ out, int n) {
  int wid = (blockIdx.x * blockDim.x + threadIdx.x) >> 6;
  int lane = threadIdx.x & 63;
  if (wid >= n) return;
  unsigned v = *(const unsigned*)&hid[(size_t)wid * ld + lane * 2];
  const float2 ww = *(const float2*)&w[lane * 2];
  float sum = waveReduceSum(b2f((unsigned short)(v & 0xFFFF)) * ww.x +
                            b2f((unsigned short)(v >> 16)) * ww.y);
  if (lane == 0) out[wid] = 1.0f / (1.0f + __expf(-(sum + b[0])));
}

extern "C" void kernel_launch(void* const* d_in, const int* in_sizes, int n_in,
                              void* d_out, int out_size, void* d_ws, size_t ws_size,
                              hipStream_t stream) {
  const float* x_client = (const float*)d_in[0];
  const float* x_sku    = (const float*)d_in[1];
  const int* cs_src = (const int*)d_in[2];
  const int* cs_dst = (const int*)d_in[3];
  const int* sc_src = (const int*)d_in[4];
  const int* sc_dst = (const int*)d_in[5];
  const float* W1l_cs = (const float*)d_in[6];
  const float* b1_cs  = (const float*)d_in[7];
  const float* W1r_cs = (const float*)d_in[8];
  const float* W1l_sc = (const float*)d_in[9];
  const float* b1_sc  = (const float*)d_in[10];
  const float* W1r_sc = (const float*)d_in[11];
  const float* Wlin1_c = (const float*)d_in[12];
  const float* blin1_c = (const float*)d_in[13];
  const float* Wlin1_s = (const float*)d_in[14];
  const float* blin1_s = (const float*)d_in[15];
  // d_in[16..18], d_in[24..25] dead (sku-side layer-2 never used)
  const float* W2l_sc = (const float*)d_in[19];
  const float* b2_sc  = (const float*)d_in[20];
  const float* W2r_sc = (const float*)d_in[21];
  const float* Wlin2_c = (const float*)d_in[22];
  const float* blin2_c = (const float*)d_in[23];
  const float* Wch1 = (const float*)d_in[26];
  const float* bch1 = (const float*)d_in[27];
  const float* Wch2 = (const float*)d_in[28];
  const float* bch2 = (const float*)d_in[29];
  const float* Wcat1 = (const float*)d_in[30];
  const float* bcat1 = (const float*)d_in[31];
  const float* Wcat2 = (const float*)d_in[32];
  const float* bcat2 = (const float*)d_in[33];
  const float* Wsk1 = (const float*)d_in[34];
  const float* bsk1 = (const float*)d_in[35];
  const float* Wsk2 = (const float*)d_in[36];
  const float* bsk2 = (const float*)d_in[37];

  const int D = 128;
  const int Nc = in_sizes[0] / D;
  const int Ns = in_sizes[1] / D;
  const int E  = in_sizes[2];
  const int NCAT = in_sizes[33];
  const int NSKU = in_sizes[37];

  const int NTc = (Nc + 127) / 128;        // 782 m-tiles (client)
  const int NTs = (Ns + 127) / 128;        // 157 m-tiles (sku)
  const int Ncp = NTc * 128;               // 100096
  const int Nsp = NTs * 128;               // 20096
  const int NCATp = ((NCAT + 127) / 128) * 128;  // 256
  const int NSKUp = ((NSKU + 127) / 128) * 128;  // 1024

  // ---- workspace layout (bf16 = ushort) ----
  char* wsb = (char*)d_ws;
  size_t o = 0;
  auto alloc = [&](size_t bytes) -> char* {
    char* p = wsb + o;
    o = (o + bytes + 255) & ~(size_t)255;
    return p;
  };
  unsigned short* concat_s = (unsigned short*)alloc((size_t)Nsp * 256 * 2);  // [mean_cs || xs]
  unsigned short* concat_c = (unsigned short*)alloc((size_t)Ncp * 256 * 2);  // [mean_sc || xc]
  unsigned short* h1_s     = (unsigned short*)alloc((size_t)Nsp * 256 * 2);
  unsigned short* big      = (unsigned short*)alloc((size_t)Ncp * 512 * 2);  // concat2 -> hidden
  unsigned short* emb_bf   = (unsigned short*)alloc((size_t)Ncp * 128 * 2);
  unsigned short* wc1s = (unsigned short*)alloc(256 * 256 * 2);
  float* bc1s = (float*)alloc(256 * 4);
  unsigned short* wc1c = (unsigned short*)alloc(256 * 256 * 2);
  float* bc1c = (float*)alloc(256 * 4);
  unsigned short* wc2c = (unsigned short*)alloc(128 * 512 * 2);
  float* bc2c = (float*)alloc(128 * 4);
  unsigned short* whh  = (unsigned short*)alloc(384 * 128 * 2);
  float* bhh  = (float*)alloc(384 * 4);
  unsigned short* wcat2p = (unsigned short*)alloc((size_t)NCATp * 128 * 2);
  unsigned short* wsk2p  = (unsigned short*)alloc((size_t)NSKUp * 128 * 2);
  int* cs_off = (int*)alloc((size_t)(Ns + 1) * 4);
  int* sc_off = (int*)alloc((size_t)(Nc + 1) * 4);
  int* zbase  = (int*)alloc((size_t)(2 * Ns + 2 * Nc) * 4);
  int* cs_cnt = zbase;
  int* sc_cnt = cs_cnt + Ns;
  int* cs_cur = sc_cnt + Nc;
  int* sc_cur = cs_cur + Ns;
  int* cs_lst = (int*)alloc((size_t)E * 4);
  int* sc_lst = (int*)alloc((size_t)E * 4);
  int* partials = (int*)alloc(1024 * 4);

  unsigned short* hidden = big;  // reuse: concat2 dead after GEMM2

  float* out_churn = (float*)d_out;
  float* out_cat = out_churn + (size_t)Nc;
  float* out_sku = out_cat + (size_t)Nc * NCAT;
  float* out_emb = out_sku + (size_t)Nc * NSKU;

  hipMemsetAsync(zbase, 0, (size_t)(2 * Ns + 2 * Nc) * 4, stream);

  // ---- weight folding (bf16) ----
  k_prep_comb<<<(256 * 256 + 255) / 256, 256, 0, stream>>>(
      W1l_cs, W1r_cs, Wlin1_s, b1_cs, blin1_s, wc1s, bc1s, 256, 128);
  k_prep_comb<<<(256 * 256 + 255) / 256, 256, 0, stream>>>(
      W1l_sc, W1r_sc, Wlin1_c, b1_sc, blin1_c, wc1c, bc1c, 256, 128);
  k_prep_comb<<<(128 * 512 + 255) / 256, 256, 0, stream>>>(
      W2l_sc, W2r_sc, Wlin2_c, b2_sc, blin2_c, wc2c, bc2c, 128, 256);
  k_prep_heads<<<(384 * 128 + 255) / 256, 256, 0, stream>>>(
      Wch1, bch1, Wcat1, bcat1, Wsk1, bsk1, whh, bhh);
  k_cast_pad<<<(NCATp * 128 + 255) / 256, 256, 0, stream>>>(Wcat2, wcat2p, NCAT, NCATp, 128);
  k_cast_pad<<<(NSKUp * 128 + 255) / 256, 256, 0, stream>>>(Wsk2, wsk2p, NSKU, NSKUp, 128);

  // ---- l2norm into right half of concat buffers ----
  k_l2norm<<<(Nc + 3) / 4, 256, 0, stream>>>(x_client, concat_c, 256, 128, Nc);
  k_l2norm<<<(Ns + 3) / 4, 256, 0, stream>>>(x_sku, concat_s, 256, 128, Ns);

  // ---- CSR build ----
  k_hist<<<(E + 255) / 256, 256, 0, stream>>>(cs_dst, cs_cnt, E);
  k_hist<<<(E + 255) / 256, 256, 0, stream>>>(sc_dst, sc_cnt, E);

  int nb_cs = (Ns + 2047) / 2048;
  k_scan1<<<nb_cs, 256, 0, stream>>>(cs_cnt, cs_off, partials, Ns);
  k_scan2<<<1, 256, 0, stream>>>(partials, nb_cs);
  k_scan3<<<nb_cs, 256, 0, stream>>>(cs_off, partials, Ns);
  k_settail<<<1, 1, 0, stream>>>(cs_off, Ns, E);

  int nb_sc = (Nc + 2047) / 2048;
  k_scan1<<<nb_sc, 256, 0, stream>>>(sc_cnt, sc_off, partials, Nc);
  k_scan2<<<1, 256, 0, stream>>>(partials, nb_sc);
  k_scan3<<<nb_sc, 256, 0, stream>>>(sc_off, partials, Nc);
  k_settail<<<1, 1, 0, stream>>>(sc_off, Nc, E);

  k_scatter<<<(E + 255) / 256, 256, 0, stream>>>(cs_src, cs_dst, cs_off, cs_cur, cs_lst, E);
  k_scatter<<<(E + 255) / 256, 256, 0, stream>>>(sc_src, sc_dst, sc_off, sc_cur, sc_lst, E);

  // ---- layer-1 mean aggregation ----
  k_agg_mean128<<<(Ns + 3) / 4, 256, 0, stream>>>(concat_c, 256, 128, cs_off, cs_lst,
                                                  concat_s, 256, 0, Ns);
  k_agg_mean128<<<(Nc + 3) / 4, 256, 0, stream>>>(concat_s, 256, 128, sc_off, sc_lst,
                                                  concat_c, 256, 0, Nc);

  // ---- layer-1 GEMMs (relu, bf16 out) ----
  k_gemm_mfma<1, 1><<<NTs * 2, 256, 0, stream>>>(
      concat_s, 256, wc1s, 256, bc1s, nullptr, 0, h1_s, 256, Ns, 256, 256, 2);
  k_gemm_mfma<1, 1><<<NTc * 2, 256, 0, stream>>>(
      concat_c, 256, wc1c, 256, bc1c, nullptr, 0, big + 256, 512, Nc, 256, 256, 2);

  // ---- layer-2 aggregation of h1_s over sc CSR ----
  k_agg_mean256<<<(Nc + 3) / 4, 256, 0, stream>>>(h1_s, 256, 0, sc_off, sc_lst, big, 512, 0, Nc);

  // ---- layer-2 GEMM -> user_emb (f32 to d_out, bf16 copy for heads) ----
  k_gemm_mfma<0, 2><<<NTc * 1, 256, 0, stream>>>(
      big, 512, wc2c, 512, bc2c, out_emb, 128, emb_bf, 128, Nc, 128, 512, 1);

  // ---- fused head hidden (relu, bf16): 384 cols, reuses `big` ----
  k_gemm_mfma<1, 1><<<NTc * 3, 256, 0, stream>>>(
      emb_bf, 128, whh, 128, bhh, nullptr, 0, hidden, 384, Nc, 384, 128, 3);

  // ---- heads ----
  k_churn<<<(Nc + 3) / 4, 256, 0, stream>>>(hidden, 384, Wch2, bch2, out_churn, Nc);
  k_gemm_mfma<2, 0><<<NTc * (NCATp / 128), 256, 0, stream>>>(
      hidden + 128, 384, wcat2p, 128, bcat2, out_cat, NCAT, nullptr, 0,
      Nc, NCAT, 128, NCATp / 128);
  k_gemm_mfma<2, 0><<<NTc * (NSKUp / 128), 256, 0, stream>>>(
      hidden + 256, 384, wsk2p, 128, bsk2, out_sku, NSKU, nullptr, 0,
      Nc, NSKU, 128, NSKUp / 128);
}

// Round 3
// 763.771 us; speedup vs baseline: 1.9194x; 1.0772x over previous
//
#include <hip/hip_runtime.h>
#include <hip/hip_bf16.h>
#include <cstdint>

// ---------------------------------------------------------------------------
// FullModel: hetero-GraphSAGE (2 layers) + 3 MLP heads.
// R3: aggressive fusion. 12 dispatches total:
//   memset, prep_all, l2norm_both, hist_both, scan1/2/3 (concatenated CSR),
//   scatter_both, agg128_both, gemm1_both (layer-1 both node types),
//   agg256 (layer-2), k_tail (GEMM2 + head-hidden + churn/cat/sku heads,
//   LDS-resident intermediates, transposed head GEMMs with float4 stores).
// All GEMMs: mfma_f32_16x16x32_bf16, fp32 accumulate, 128x128 tiles,
// global_load_lds(16B) staging, both-sides XOR swizzle (G21).
// ---------------------------------------------------------------------------

typedef __attribute__((ext_vector_type(8))) short bf16x8;
typedef __attribute__((ext_vector_type(4))) float f32x4;

__device__ __forceinline__ float b2f(unsigned short u) {
  return __uint_as_float(((unsigned)u) << 16);
}
__device__ __forceinline__ unsigned short f2b(float f) {
  unsigned u = __float_as_uint(f);
  return (unsigned short)((u + 0x7FFFu + ((u >> 16) & 1u)) >> 16);
}
__device__ __forceinline__ float sigmoidf_(float v) {
  return 1.0f / (1.0f + __expf(-v));
}

__device__ __forceinline__ float waveReduceSum(float v) {
  #pragma unroll
  for (int s = 32; s > 0; s >>= 1) v += __shfl_xor(v, s, 64);
  return v;
}

__device__ __forceinline__ void gload16(const void* g, void* l) {
  __builtin_amdgcn_global_load_lds(
      (const __attribute__((address_space(1))) unsigned int*)g,
      (__attribute__((address_space(3))) unsigned int*)l, 16, 0, 0);
}

// stage a [128 rows][32 k] bf16 tile into 8KB LDS (linear dest, pre-swizzled
// source: physical 16B-slot (p&3) of row rr holds logical k-group (p&3)^(rr&3))
__device__ __forceinline__ void stage_tile(const unsigned short* __restrict__ G,
                                           int ld, unsigned short* lds,
                                           int wave, int lane) {
  #pragma unroll
  for (int j = 0; j < 2; ++j) {
    const int p = wave * 128 + j * 64 + lane;
    const int rr = p >> 2;
    const int sl = (p & 3) ^ (rr & 3);
    gload16(G + (size_t)rr * ld + (sl << 3), lds + ((wave * 128 + j * 64) << 3));
  }
}

// read an 8-element bf16 fragment from a staged [rows][32] tile
__device__ __forceinline__ bf16x8 read_frag32(const unsigned short* lds, int row, int kg) {
  const int srd = kg ^ (row & 3);
  return *(const bf16x8*)&lds[row * 32 + (srd << 3)];
}

// [128][128] bf16 LDS tile, 16B-slot swizzle: phys = logical ^ (row&7)
__device__ __forceinline__ bf16x8 read_frag128(const unsigned short* lds, int row, int kslot) {
  const int ps = kslot ^ (row & 7);
  return *(const bf16x8*)&lds[row * 128 + (ps << 3)];
}
__device__ __forceinline__ void write_elem128(unsigned short* lds, int row, int col,
                                              unsigned short v) {
  const int slot = (col >> 3) ^ (row & 7);
  lds[row * 128 + (slot << 3) + (col & 7)] = v;
}

// ---- all cold-path weight prep in one dispatch (i covers max segment) ----
__global__ void k_prep_all(
    const float* __restrict__ W1l_cs, const float* __restrict__ W1r_cs,
    const float* __restrict__ Wlin1_s, const float* __restrict__ b1_cs,
    const float* __restrict__ blin1_s,
    const float* __restrict__ W1l_sc, const float* __restrict__ W1r_sc,
    const float* __restrict__ Wlin1_c, const float* __restrict__ b1_sc,
    const float* __restrict__ blin1_c,
    const float* __restrict__ W2l_sc, const float* __restrict__ W2r_sc,
    const float* __restrict__ Wlin2_c, const float* __restrict__ b2_sc,
    const float* __restrict__ blin2_c,
    const float* __restrict__ Wch1, const float* __restrict__ bch1,
    const float* __restrict__ Wcat1, const float* __restrict__ bcat1,
    const float* __restrict__ Wsk1, const float* __restrict__ bsk1,
    const float* __restrict__ Wcat2, const float* __restrict__ Wsk2,
    unsigned short* __restrict__ wc1s, float* __restrict__ bc1s,
    unsigned short* __restrict__ wc1c, float* __restrict__ bc1c,
    unsigned short* __restrict__ wc2c, float* __restrict__ bc2c,
    unsigned short* __restrict__ whh, float* __restrict__ bhh,
    unsigned short* __restrict__ wcat2p, unsigned short* __restrict__ wsk2p,
    int NCAT, int NCATp, int NSKU, int NSKUp) {
  const int i = blockIdx.x * blockDim.x + threadIdx.x;
  if (i < 65536) {
    {  // layer-1 combined weights [256][256], Kh=128
      int n = i >> 8, k = i & 255;
      wc1s[i] = f2b(k < 128 ? W1l_cs[n * 128 + k]
                            : W1r_cs[n * 128 + k - 128] + Wlin1_s[n * 128 + k - 128]);
      wc1c[i] = f2b(k < 128 ? W1l_sc[n * 128 + k]
                            : W1r_sc[n * 128 + k - 128] + Wlin1_c[n * 128 + k - 128]);
    }
    {  // layer-2 combined weight [128][512], Kh=256
      int n = i >> 9, k = i & 511;
      wc2c[i] = f2b(k < 256 ? W2l_sc[n * 256 + k]
                            : W2r_sc[n * 256 + k - 256] + Wlin2_c[n * 256 + k - 256]);
    }
  }
  if (i < 256) { bc1s[i] = b1_cs[i] + blin1_s[i]; bc1c[i] = b1_sc[i] + blin1_c[i]; }
  if (i < 128) bc2c[i] = b2_sc[i] + blin2_c[i];
  if (i < 384 * 128) {
    int n = i >> 7, k = i & 127;
    const float* w = n < 128 ? Wch1 : (n < 256 ? Wcat1 : Wsk1);
    whh[i] = f2b(w[(n & 127) * 128 + k]);
  }
  if (i < 384) bhh[i] = i < 128 ? bch1[i] : (i < 256 ? bcat1[i - 128] : bsk1[i - 256]);
  if (i < NCATp * 128) wcat2p[i] = (i >> 7) < NCAT ? f2b(Wcat2[i]) : (unsigned short)0;
  if (i < NSKUp * 128) wsk2p[i] = (i >> 7) < NSKU ? f2b(Wsk2[i]) : (unsigned short)0;
}

// ---- l2norm both node sets -> right half of concat buffers ----
__global__ void k_l2norm_both(const float* __restrict__ xc, const float* __restrict__ xs,
                              unsigned short* __restrict__ concat_c,
                              unsigned short* __restrict__ concat_s, int Nc, int Ns) {
  int wid = (blockIdx.x * blockDim.x + threadIdx.x) >> 6;
  int lane = threadIdx.x & 63;
  const float* x;
  unsigned short* out;
  if (wid < Nc) {
    x = xc + (size_t)wid * 128;
    out = concat_c + (size_t)wid * 256 + 128;
  } else {
    int w = wid - Nc;
    if (w >= Ns) return;
    x = xs + (size_t)w * 128;
    out = concat_s + (size_t)w * 256 + 128;
  }
  const float2 v = *(const float2*)&x[lane * 2];
  float ss = waveReduceSum(v.x * v.x + v.y * v.y);
  float sc = 1.0f / fmaxf(sqrtf(ss), 1e-12f);
  out[lane * 2] = f2b(v.x * sc);
  out[lane * 2 + 1] = f2b(v.y * sc);
}

// ---- histogram over both edge sets into concatenated counters ----
__global__ void k_hist_both(const int* __restrict__ cs_dst, const int* __restrict__ sc_dst,
                            int* __restrict__ cnt, int E, int Ns) {
  int i = blockIdx.x * blockDim.x + threadIdx.x;
  if (i < E) atomicAdd(&cnt[cs_dst[i]], 1);
  else if (i < 2 * E) atomicAdd(&cnt[Ns + sc_dst[i - E]], 1);
}

// ---- exclusive scan, nin inputs -> nout = nin+1 outputs (incl. total) ----
__global__ void k_scan1(const int* __restrict__ in, int* __restrict__ out,
                        int* __restrict__ partials, int nin, int nout) {
  __shared__ int sd[256];
  const int tid = threadIdx.x;
  const int base = blockIdx.x * 2048 + tid * 8;
  int v[8];
  int tsum = 0;
  #pragma unroll
  for (int u = 0; u < 8; ++u) {
    int idx = base + u;
    int t = (idx < nin) ? in[idx] : 0;
    v[u] = tsum; tsum += t;
  }
  sd[tid] = tsum;
  __syncthreads();
  for (int offp = 1; offp < 256; offp <<= 1) {
    int t = (tid >= offp) ? sd[tid - offp] : 0;
    __syncthreads();
    sd[tid] += t;
    __syncthreads();
  }
  int texcl = (tid == 0) ? 0 : sd[tid - 1];
  if (tid == 255) partials[blockIdx.x] = sd[255];
  #pragma unroll
  for (int u = 0; u < 8; ++u) {
    int idx = base + u;
    if (idx < nout) out[idx] = v[u] + texcl;
  }
}

__global__ void k_scan2(int* __restrict__ partials, int nb) {
  __shared__ int sd[256];
  const int tid = threadIdx.x;
  int v = (tid < nb) ? partials[tid] : 0;
  sd[tid] = v;
  __syncthreads();
  for (int offp = 1; offp < 256; offp <<= 1) {
    int t = (tid >= offp) ? sd[tid - offp] : 0;
    __syncthreads();
    sd[tid] += t;
    __syncthreads();
  }
  if (tid < nb) partials[tid] = (tid == 0) ? 0 : sd[tid - 1];
}

__global__ void k_scan3(int* __restrict__ out, const int* __restrict__ partials, int nout) {
  int add = partials[blockIdx.x];
  int base = blockIdx.x * 2048 + threadIdx.x * 8;
  #pragma unroll
  for (int u = 0; u < 8; ++u) {
    int idx = base + u;
    if (idx < nout) out[idx] += add;
  }
}

// ---- scatter both edge sets into one adjacency array (absolute offsets) ----
__global__ void k_scatter_both(const int* __restrict__ cs_src, const int* __restrict__ cs_dst,
                               const int* __restrict__ sc_src, const int* __restrict__ sc_dst,
                               const int* __restrict__ off, int* __restrict__ cur,
                               int* __restrict__ lst, int E, int Ns) {
  int i = blockIdx.x * blockDim.x + threadIdx.x;
  if (i >= 2 * E) return;
  int d, s;
  if (i < E) { d = cs_dst[i]; s = cs_src[i]; }
  else { d = Ns + sc_dst[i - E]; s = sc_src[i - E]; }
  int p = atomicAdd(&cur[d], 1);
  lst[off[d] + p] = s;
}

// ---- layer-1 mean aggregation, both directions, one wave per destination ----
__global__ void k_agg128_both(const unsigned short* __restrict__ concat_c,
                              const unsigned short* __restrict__ concat_s,
                              const int* __restrict__ off, const int* __restrict__ lst,
                              unsigned short* __restrict__ out_s,
                              unsigned short* __restrict__ out_c, int Ns, int Nc) {
  int wid = (blockIdx.x * blockDim.x + threadIdx.x) >> 6;
  int lane = threadIdx.x & 63;
  const unsigned short* feat;
  unsigned short* out;
  int s, e;
  if (wid < Ns) {
    s = off[wid]; e = off[wid + 1];
    feat = concat_c; out = out_s + (size_t)wid * 256;
  } else {
    int w = wid - Ns;
    if (w >= Nc) return;
    s = off[Ns + w]; e = off[Ns + w + 1];
    feat = concat_s; out = out_c + (size_t)w * 256;
  }
  float ax = 0.f, ay = 0.f;
  for (int i = s; i < e; ++i) {
    int r = lst[i];
    unsigned v = *(const unsigned*)&feat[(size_t)r * 256 + 128 + lane * 2];
    ax += b2f((unsigned short)(v & 0xFFFF));
    ay += b2f((unsigned short)(v >> 16));
  }
  float inv = 1.0f / (float)((e - s) > 0 ? (e - s) : 1);
  out[lane * 2] = f2b(ax * inv);
  out[lane * 2 + 1] = f2b(ay * inv);
}

// ---- layer-2 mean aggregation (256-wide) ----
__global__ void k_agg_mean256(const unsigned short* __restrict__ feat,
                              const int* __restrict__ off, const int* __restrict__ lst,
                              unsigned short* __restrict__ out, int ostride, int n) {
  int wid = (blockIdx.x * blockDim.x + threadIdx.x) >> 6;
  int lane = threadIdx.x & 63;
  if (wid >= n) return;
  int s = off[wid], e = off[wid + 1];
  float a0 = 0.f, a1 = 0.f, a2 = 0.f, a3 = 0.f;
  for (int i = s; i < e; ++i) {
    int r = lst[i];
    uint2 v = *(const uint2*)&feat[(size_t)r * 256 + lane * 4];
    a0 += b2f((unsigned short)(v.x & 0xFFFF));
    a1 += b2f((unsigned short)(v.x >> 16));
    a2 += b2f((unsigned short)(v.y & 0xFFFF));
    a3 += b2f((unsigned short)(v.y >> 16));
  }
  float inv = 1.0f / (float)((e - s) > 0 ? (e - s) : 1);
  unsigned short* o = &out[(size_t)wid * ostride + lane * 4];
  o[0] = f2b(a0 * inv); o[1] = f2b(a1 * inv); o[2] = f2b(a2 * inv); o[3] = f2b(a3 * inv);
}

// ---- layer-1 GEMMs for both node types in one dispatch ----
// C = relu(A[M,256] @ W[256,256]^T + b), bf16 out. sku part: wg < NTs2.
__global__ __launch_bounds__(256) void k_gemm1_both(
    const unsigned short* __restrict__ As_g, const unsigned short* __restrict__ Ws_g,
    const float* __restrict__ bs_g, unsigned short* __restrict__ Cs_g, int Ms, int NTs2,
    const unsigned short* __restrict__ Ac_g, const unsigned short* __restrict__ Wc_g,
    const float* __restrict__ bc_g, unsigned short* __restrict__ Cc_g, int Mc) {
  __shared__ __align__(16) unsigned short As[4096];
  __shared__ __align__(16) unsigned short Bs[4096];
  // bijective XCD swizzle (m204)
  const int nwg = gridDim.x, orig = blockIdx.x;
  const int q8 = nwg >> 3, r8 = nwg & 7;
  const int xcd = orig & 7, cidx = orig >> 3;
  int wg = (xcd < r8 ? xcd * (q8 + 1) : r8 * (q8 + 1) + (xcd - r8) * q8) + cidx;

  const unsigned short *A, *W;
  const float* bias;
  unsigned short* C;
  int M, ldc;
  if (wg < NTs2) { A = As_g; W = Ws_g; bias = bs_g; C = Cs_g; M = Ms; ldc = 256; }
  else { wg -= NTs2; A = Ac_g; W = Wc_g; bias = bc_g; C = Cc_g; M = Mc; ldc = 512; }
  const int bm = (wg >> 1) * 128, bn = (wg & 1) * 128;

  const int tid = threadIdx.x, lane = tid & 63, wave = tid >> 6;
  const int wm = (wave >> 1) << 6, wn = (wave & 1) << 6;
  const int l15 = lane & 15, l4 = lane >> 4;

  f32x4 acc[4][4] = {};
  for (int k0 = 0; k0 < 256; k0 += 32) {
    stage_tile(A + (size_t)bm * 256 + k0, 256, As, wave, lane);
    stage_tile(W + (size_t)bn * 256 + k0, 256, Bs, wave, lane);
    __syncthreads();
    bf16x8 af[4], bfr[4];
    #pragma unroll
    for (int i = 0; i < 4; ++i) {
      af[i] = read_frag32(As, wm + i * 16 + l15, l4);
      bfr[i] = read_frag32(Bs, wn + i * 16 + l15, l4);
    }
    #pragma unroll
    for (int i = 0; i < 4; ++i)
      #pragma unroll
      for (int j = 0; j < 4; ++j)
        acc[i][j] = __builtin_amdgcn_mfma_f32_16x16x32_bf16(af[i], bfr[j], acc[i][j], 0, 0, 0);
    __syncthreads();
  }
  #pragma unroll
  for (int j = 0; j < 4; ++j) {
    int col = bn + wn + j * 16 + l15;
    float bj = bias[col];
    #pragma unroll
    for (int i = 0; i < 4; ++i) {
      int r0 = bm + wm + i * 16 + (l4 << 2);
      #pragma unroll
      for (int q = 0; q < 4; ++q) {
        int row = r0 + q;
        if (row < M) C[(size_t)row * ldc + col] = f2b(fmaxf(acc[i][j][q] + bj, 0.0f));
      }
    }
  }
}

// ---- fused tail: emb = concat2 @ W2^T + b2 (-> d_out fp32 + LDS bf16);
//      per head chunk: h = relu(emb @ Whh^T + b) in LDS; head GEMM from LDS.
//      Head GEMMs computed transposed (A=W_head, B=h) -> float4 output stores.
__global__ __launch_bounds__(256) void k_tail(
    const unsigned short* __restrict__ A2,   // concat2 [Ncp][512]
    const unsigned short* __restrict__ W2, const float* __restrict__ b2,
    const unsigned short* __restrict__ Whh, const float* __restrict__ bhh,
    const float* __restrict__ wch2, const float* __restrict__ bch2,
    const unsigned short* __restrict__ Wcat, const float* __restrict__ bcat, int NCAT, int ncat_ch,
    const unsigned short* __restrict__ Wsku, const float* __restrict__ bsku, int NSKU, int nsku_ch,
    float* __restrict__ out_emb, float* __restrict__ out_churn,
    float* __restrict__ out_cat, float* __restrict__ out_sku, int M) {
  __shared__ __align__(16) unsigned short As[4096];
  __shared__ __align__(16) unsigned short Bs[4096];
  __shared__ __align__(16) unsigned short embT[16384];  // [128][128] swizzled
  __shared__ __align__(16) unsigned short hT[16384];

  const int bm = blockIdx.x * 128;
  const int tid = threadIdx.x, lane = tid & 63, wave = tid >> 6;
  const int wm = (wave >> 1) << 6, wn = (wave & 1) << 6;
  const int l15 = lane & 15, l4 = lane >> 4;

  // ---- Phase E: emb (no activation) ----
  {
    f32x4 acc[4][4] = {};
    for (int k0 = 0; k0 < 512; k0 += 32) {
      stage_tile(A2 + (size_t)bm * 512 + k0, 512, As, wave, lane);
      stage_tile(W2 + k0, 512, Bs, wave, lane);
      __syncthreads();
      bf16x8 af[4], bfr[4];
      #pragma unroll
      for (int i = 0; i < 4; ++i) {
        af[i] = read_frag32(As, wm + i * 16 + l15, l4);
        bfr[i] = read_frag32(Bs, wn + i * 16 + l15, l4);
      }
      #pragma unroll
      for (int i = 0; i < 4; ++i)
        #pragma unroll
        for (int j = 0; j < 4; ++j)
          acc[i][j] = __builtin_amdgcn_mfma_f32_16x16x32_bf16(af[i], bfr[j], acc[i][j], 0, 0, 0);
      __syncthreads();
    }
    #pragma unroll
    for (int j = 0; j < 4; ++j) {
      int col = wn + j * 16 + l15;
      float bj = b2[col];
      #pragma unroll
      for (int i = 0; i < 4; ++i) {
        int r0 = wm + i * 16 + (l4 << 2);
        #pragma unroll
        for (int q = 0; q < 4; ++q) {
          float v = acc[i][j][q] + bj;
          int rl = r0 + q;
          if (bm + rl < M) out_emb[(size_t)(bm + rl) * 128 + col] = v;
          write_elem128(embT, rl, col, f2b(v));
        }
      }
    }
  }
  __syncthreads();

  // ---- per head chunk: 0=churn, 1=cat, 2=sku ----
  for (int hc = 0; hc < 3; ++hc) {
    // hidden chunk: h = relu(embT @ Whh[hc]^T + bhh[hc])
    {
      f32x4 hacc[4][4] = {};
      for (int k0 = 0; k0 < 128; k0 += 32) {
        stage_tile(Whh + (size_t)hc * 128 * 128 + k0, 128, Bs, wave, lane);
        __syncthreads();
        bf16x8 af[4], bfr[4];
        const int kslot = (k0 >> 3) + l4;
        #pragma unroll
        for (int i = 0; i < 4; ++i) {
          af[i] = read_frag128(embT, wm + i * 16 + l15, kslot);
          bfr[i] = read_frag32(Bs, wn + i * 16 + l15, l4);
        }
        #pragma unroll
        for (int i = 0; i < 4; ++i)
          #pragma unroll
          for (int j = 0; j < 4; ++j)
            hacc[i][j] = __builtin_amdgcn_mfma_f32_16x16x32_bf16(af[i], bfr[j], hacc[i][j], 0, 0, 0);
        __syncthreads();
      }
      #pragma unroll
      for (int j = 0; j < 4; ++j) {
        int col = wn + j * 16 + l15;
        float bj = bhh[hc * 128 + col];
        #pragma unroll
        for (int i = 0; i < 4; ++i) {
          int r0 = wm + i * 16 + (l4 << 2);
          #pragma unroll
          for (int q = 0; q < 4; ++q)
            write_elem128(hT, r0 + q, col, f2b(fmaxf(hacc[i][j][q] + bj, 0.0f)));
        }
      }
    }
    __syncthreads();  // hT ready

    if (hc == 0) {
      // churn: thread t < 128 owns row t; staggered swizzled LDS reads
      if (tid < 128) {
        const int row = tid;
        float s = 0.f;
        #pragma unroll
        for (int ks = 0; ks < 16; ++ks) {
          const int L = (ks + row) & 15;
          const bf16x8 hv = *(const bf16x8*)&hT[row * 128 + ((L ^ (row & 7)) << 3)];
          #pragma unroll
          for (int e = 0; e < 8; ++e)
            s += b2f((unsigned short)hv[e]) * wch2[L * 8 + e];
        }
        if (bm + row < M) out_churn[bm + row] = sigmoidf_(s + bch2[0]);
      }
      __syncthreads();
    } else {
      const unsigned short* Wh = (hc == 1) ? Wcat : Wsku;
      const float* bh = (hc == 1) ? bcat : bsku;
      float* oh = (hc == 1) ? out_cat : out_sku;
      const int Nh = (hc == 1) ? NCAT : NSKU;
      const int nch = (hc == 1) ? ncat_ch : nsku_ch;
      for (int c = 0; c < nch; ++c) {
        f32x4 oacc[4][4] = {};
        for (int k0 = 0; k0 < 128; k0 += 32) {
          stage_tile(Wh + ((size_t)c * 128) * 128 + k0, 128, As, wave, lane);
          __syncthreads();
          bf16x8 af[4], bfr[4];
          const int kslot = (k0 >> 3) + l4;
          #pragma unroll
          for (int i = 0; i < 4; ++i) {
            af[i] = read_frag32(As, wm + i * 16 + l15, l4);
            bfr[i] = read_frag128(hT, wn + i * 16 + l15, kslot);
          }
          #pragma unroll
          for (int i = 0; i < 4; ++i)
            #pragma unroll
            for (int j = 0; j < 4; ++j)
              oacc[i][j] = __builtin_amdgcn_mfma_f32_16x16x32_bf16(af[i], bfr[j], oacc[i][j], 0, 0, 0);
          __syncthreads();
        }
        // transposed epilogue: D[a=headcol][b=local row]
        #pragma unroll
        for (int i = 0; i < 4; ++i) {
          const int n0 = c * 128 + wm + i * 16 + (l4 << 2);
          if (n0 < Nh) {  // Nh % 4 == 0 -> whole quad valid
            const float4 bv = *(const float4*)&bh[n0];
            #pragma unroll
            for (int j = 0; j < 4; ++j) {
              const int m = wn + j * 16 + l15;
              if (bm + m < M) {
                float4 ov;
                ov.x = sigmoidf_(oacc[i][j][0] + bv.x);
                ov.y = sigmoidf_(oacc[i][j][1] + bv.y);
                ov.z = sigmoidf_(oacc[i][j][2] + bv.z);
                ov.w = sigmoidf_(oacc[i][j][3] + bv.w);
                *(float4*)&oh[(size_t)(bm + m) * Nh + n0] = ov;
              }
            }
          }
        }
      }
      __syncthreads();
    }
  }
}

extern "C" void kernel_launch(void* const* d_in, const int* in_sizes, int n_in,
                              void* d_out, int out_size, void* d_ws, size_t ws_size,
                              hipStream_t stream) {
  const float* x_client = (const float*)d_in[0];
  const float* x_sku    = (const float*)d_in[1];
  const int* cs_src = (const int*)d_in[2];
  const int* cs_dst = (const int*)d_in[3];
  const int* sc_src = (const int*)d_in[4];
  const int* sc_dst = (const int*)d_in[5];
  const float* W1l_cs = (const float*)d_in[6];
  const float* b1_cs  = (const float*)d_in[7];
  const float* W1r_cs = (const float*)d_in[8];
  const float* W1l_sc = (const float*)d_in[9];
  const float* b1_sc  = (const float*)d_in[10];
  const float* W1r_sc = (const float*)d_in[11];
  const float* Wlin1_c = (const float*)d_in[12];
  const float* blin1_c = (const float*)d_in[13];
  const float* Wlin1_s = (const float*)d_in[14];
  const float* blin1_s = (const float*)d_in[15];
  const float* W2l_sc = (const float*)d_in[19];
  const float* b2_sc  = (const float*)d_in[20];
  const float* W2r_sc = (const float*)d_in[21];
  const float* Wlin2_c = (const float*)d_in[22];
  const float* blin2_c = (const float*)d_in[23];
  const float* Wch1 = (const float*)d_in[26];
  const float* bch1 = (const float*)d_in[27];
  const float* Wch2 = (const float*)d_in[28];
  const float* bch2 = (const float*)d_in[29];
  const float* Wcat1 = (const float*)d_in[30];
  const float* bcat1 = (const float*)d_in[31];
  const float* Wcat2 = (const float*)d_in[32];
  const float* bcat2 = (const float*)d_in[33];
  const float* Wsk1 = (const float*)d_in[34];
  const float* bsk1 = (const float*)d_in[35];
  const float* Wsk2 = (const float*)d_in[36];
  const float* bsk2 = (const float*)d_in[37];

  const int D = 128;
  const int Nc = in_sizes[0] / D;
  const int Ns = in_sizes[1] / D;
  const int E  = in_sizes[2];
  const int NCAT = in_sizes[33];
  const int NSKU = in_sizes[37];

  const int NTc = (Nc + 127) / 128;
  const int NTs = (Ns + 127) / 128;
  const int Ncp = NTc * 128;
  const int Nsp = NTs * 128;
  const int NCATp = ((NCAT + 127) / 128) * 128;
  const int NSKUp = ((NSKU + 127) / 128) * 128;

  // ---- workspace layout ----
  char* wsb = (char*)d_ws;
  size_t o = 0;
  auto alloc = [&](size_t bytes) -> char* {
    char* p = wsb + o;
    o = (o + bytes + 255) & ~(size_t)255;
    return p;
  };
  unsigned short* concat_s = (unsigned short*)alloc((size_t)Nsp * 256 * 2);
  unsigned short* concat_c = (unsigned short*)alloc((size_t)Ncp * 256 * 2);
  unsigned short* h1_s     = (unsigned short*)alloc((size_t)Nsp * 256 * 2);
  unsigned short* big      = (unsigned short*)alloc((size_t)Ncp * 512 * 2);  // concat2
  unsigned short* wc1s = (unsigned short*)alloc(256 * 256 * 2);
  float* bc1s = (float*)alloc(256 * 4);
  unsigned short* wc1c = (unsigned short*)alloc(256 * 256 * 2);
  float* bc1c = (float*)alloc(256 * 4);
  unsigned short* wc2c = (unsigned short*)alloc(128 * 512 * 2);
  float* bc2c = (float*)alloc(128 * 4);
  unsigned short* whh  = (unsigned short*)alloc(384 * 128 * 2);
  float* bhh  = (float*)alloc(384 * 4);
  unsigned short* wcat2p = (unsigned short*)alloc((size_t)NCATp * 128 * 2);
  unsigned short* wsk2p  = (unsigned short*)alloc((size_t)NSKUp * 128 * 2);
  int* off   = (int*)alloc((size_t)(Ns + Nc + 1) * 4);
  int* zbase = (int*)alloc((size_t)(2 * (Ns + Nc)) * 4);  // cnt ++ cur
  int* cnt = zbase;
  int* cur = zbase + (Ns + Nc);
  int* lst = (int*)alloc((size_t)(2 * E) * 4);
  int* partials = (int*)alloc(1024 * 4);

  float* out_churn = (float*)d_out;
  float* out_cat = out_churn + (size_t)Nc;
  float* out_sku = out_cat + (size_t)Nc * NCAT;
  float* out_emb = out_sku + (size_t)Nc * NSKU;

  hipMemsetAsync(zbase, 0, (size_t)(2 * (Ns + Nc)) * 4, stream);

  // 1. weight prep (one dispatch)
  k_prep_all<<<512, 256, 0, stream>>>(
      W1l_cs, W1r_cs, Wlin1_s, b1_cs, blin1_s,
      W1l_sc, W1r_sc, Wlin1_c, b1_sc, blin1_c,
      W2l_sc, W2r_sc, Wlin2_c, b2_sc, blin2_c,
      Wch1, bch1, Wcat1, bcat1, Wsk1, bsk1, Wcat2, Wsk2,
      wc1s, bc1s, wc1c, bc1c, wc2c, bc2c, whh, bhh, wcat2p, wsk2p,
      NCAT, NCATp, NSKU, NSKUp);

  // 2. l2norm both
  k_l2norm_both<<<(Nc + Ns + 3) / 4, 256, 0, stream>>>(
      x_client, x_sku, concat_c, concat_s, Nc, Ns);

  // 3-7. CSR build (concatenated)
  const int n_nodes = Ns + Nc;
  k_hist_both<<<(2 * E + 255) / 256, 256, 0, stream>>>(cs_dst, sc_dst, cnt, E, Ns);
  const int nb = (n_nodes + 1 + 2047) / 2048;
  k_scan1<<<nb, 256, 0, stream>>>(cnt, off, partials, n_nodes, n_nodes + 1);
  k_scan2<<<1, 256, 0, stream>>>(partials, nb);
  k_scan3<<<nb, 256, 0, stream>>>(off, partials, n_nodes + 1);
  k_scatter_both<<<(2 * E + 255) / 256, 256, 0, stream>>>(
      cs_src, cs_dst, sc_src, sc_dst, off, cur, lst, E, Ns);

  // 8. layer-1 aggregation (both directions)
  k_agg128_both<<<(n_nodes + 3) / 4, 256, 0, stream>>>(
      concat_c, concat_s, off, lst, concat_s, concat_c, Ns, Nc);

  // 9. layer-1 GEMMs (merged)
  k_gemm1_both<<<NTs * 2 + NTc * 2, 256, 0, stream>>>(
      concat_s, wc1s, bc1s, h1_s, Ns, NTs * 2,
      concat_c, wc1c, bc1c, big + 256, Nc);

  // 10. layer-2 aggregation (client destinations: off + Ns)
  k_agg_mean256<<<(Nc + 3) / 4, 256, 0, stream>>>(h1_s, off + Ns, lst, big, 512, Nc);

  // 11. fused tail
  k_tail<<<NTc, 256, 0, stream>>>(
      big, wc2c, bc2c, whh, bhh, Wch2, bch2,
      wcat2p, bcat2, NCAT, NCATp / 128,
      wsk2p, bsk2, NSKU, NSKUp / 128,
      out_emb, out_churn, out_cat, out_sku, Nc);
}

// Round 4
// 690.374 us; speedup vs baseline: 2.1235x; 1.1063x over previous
//
#include <hip/hip_runtime.h>
#include <hip/hip_bf16.h>
#include <cstdint>

// ---------------------------------------------------------------------------
// FullModel: hetero-GraphSAGE (2 layers) + 3 MLP heads.
// R4: tail re-partitioned for TLP (R3's 410us fused tail was latency-bound at
// 9% occupancy). Now:
//   k_embhid: GEMM2 + 3 head-hidden chunks (embT LDS-resident), hidden->global
//   k_heads:  7820 flat blocks, one 128x128 head tile each, 2 barriers/block
//   k_churn:  wave-per-row dot
// All GEMMs: mfma_f32_16x16x32_bf16, fp32 acc, global_load_lds(16B) staging,
// both-sides XOR swizzle (G21).
// ---------------------------------------------------------------------------

typedef __attribute__((ext_vector_type(8))) short bf16x8;
typedef __attribute__((ext_vector_type(4))) float f32x4;

__device__ __forceinline__ float b2f(unsigned short u) {
  return __uint_as_float(((unsigned)u) << 16);
}
__device__ __forceinline__ unsigned short f2b(float f) {
  unsigned u = __float_as_uint(f);
  return (unsigned short)((u + 0x7FFFu + ((u >> 16) & 1u)) >> 16);
}
__device__ __forceinline__ float sigmoidf_(float v) {
  return 1.0f / (1.0f + __expf(-v));
}

__device__ __forceinline__ float waveReduceSum(float v) {
  #pragma unroll
  for (int s = 32; s > 0; s >>= 1) v += __shfl_xor(v, s, 64);
  return v;
}

__device__ __forceinline__ void gload16(const void* g, void* l) {
  __builtin_amdgcn_global_load_lds(
      (const __attribute__((address_space(1))) unsigned int*)g,
      (__attribute__((address_space(3))) unsigned int*)l, 16, 0, 0);
}

// stage a [128 rows][32 k] bf16 tile (linear LDS dest, pre-swizzled source)
__device__ __forceinline__ void stage_tile(const unsigned short* __restrict__ G,
                                           int ld, unsigned short* lds,
                                           int wave, int lane) {
  #pragma unroll
  for (int j = 0; j < 2; ++j) {
    const int p = wave * 128 + j * 64 + lane;
    const int rr = p >> 2;
    const int sl = (p & 3) ^ (rr & 3);
    gload16(G + (size_t)rr * ld + (sl << 3), lds + ((wave * 128 + j * 64) << 3));
  }
}

// stage a [128 rows][128 k] bf16 tile (2048 16B-slots, 8 per thread)
__device__ __forceinline__ void stage_tile128(const unsigned short* __restrict__ G,
                                              int ldg, unsigned short* lds,
                                              int wave, int lane) {
  #pragma unroll
  for (int u = 0; u < 8; ++u) {
    const int base = u * 256 + wave * 64;
    const int p = base + lane;
    const int row = p >> 4;
    const int sl = (p & 15) ^ (row & 7);
    gload16(G + (size_t)row * ldg + (sl << 3), lds + (base << 3));
  }
}

// read an 8-elem bf16 fragment from a staged [rows][32] tile
__device__ __forceinline__ bf16x8 read_frag32(const unsigned short* lds, int row, int kg) {
  const int srd = kg ^ (row & 3);
  return *(const bf16x8*)&lds[row * 32 + (srd << 3)];
}

// [128][128] bf16 LDS tile, 16B-slot swizzle: phys = logical ^ (row&7)
__device__ __forceinline__ bf16x8 read_frag128(const unsigned short* lds, int row, int kslot) {
  const int ps = kslot ^ (row & 7);
  return *(const bf16x8*)&lds[row * 128 + (ps << 3)];
}
__device__ __forceinline__ void write_elem128(unsigned short* lds, int row, int col,
                                              unsigned short v) {
  const int slot = (col >> 3) ^ (row & 7);
  lds[row * 128 + (slot << 3) + (col & 7)] = v;
}

// ---- all cold-path weight prep in one dispatch ----
__global__ void k_prep_all(
    const float* __restrict__ W1l_cs, const float* __restrict__ W1r_cs,
    const float* __restrict__ Wlin1_s, const float* __restrict__ b1_cs,
    const float* __restrict__ blin1_s,
    const float* __restrict__ W1l_sc, const float* __restrict__ W1r_sc,
    const float* __restrict__ Wlin1_c, const float* __restrict__ b1_sc,
    const float* __restrict__ blin1_c,
    const float* __restrict__ W2l_sc, const float* __restrict__ W2r_sc,
    const float* __restrict__ Wlin2_c, const float* __restrict__ b2_sc,
    const float* __restrict__ blin2_c,
    const float* __restrict__ Wch1, const float* __restrict__ bch1,
    const float* __restrict__ Wcat1, const float* __restrict__ bcat1,
    const float* __restrict__ Wsk1, const float* __restrict__ bsk1,
    const float* __restrict__ Wcat2, const float* __restrict__ Wsk2,
    unsigned short* __restrict__ wc1s, float* __restrict__ bc1s,
    unsigned short* __restrict__ wc1c, float* __restrict__ bc1c,
    unsigned short* __restrict__ wc2c, float* __restrict__ bc2c,
    unsigned short* __restrict__ whh, float* __restrict__ bhh,
    unsigned short* __restrict__ wcat2p, unsigned short* __restrict__ wsk2p,
    int NCAT, int NCATp, int NSKU, int NSKUp) {
  const int i = blockIdx.x * blockDim.x + threadIdx.x;
  if (i < 65536) {
    {
      int n = i >> 8, k = i & 255;
      wc1s[i] = f2b(k < 128 ? W1l_cs[n * 128 + k]
                            : W1r_cs[n * 128 + k - 128] + Wlin1_s[n * 128 + k - 128]);
      wc1c[i] = f2b(k < 128 ? W1l_sc[n * 128 + k]
                            : W1r_sc[n * 128 + k - 128] + Wlin1_c[n * 128 + k - 128]);
    }
    {
      int n = i >> 9, k = i & 511;
      wc2c[i] = f2b(k < 256 ? W2l_sc[n * 256 + k]
                            : W2r_sc[n * 256 + k - 256] + Wlin2_c[n * 256 + k - 256]);
    }
  }
  if (i < 256) { bc1s[i] = b1_cs[i] + blin1_s[i]; bc1c[i] = b1_sc[i] + blin1_c[i]; }
  if (i < 128) bc2c[i] = b2_sc[i] + blin2_c[i];
  if (i < 384 * 128) {
    int n = i >> 7, k = i & 127;
    const float* w = n < 128 ? Wch1 : (n < 256 ? Wcat1 : Wsk1);
    whh[i] = f2b(w[(n & 127) * 128 + k]);
  }
  if (i < 384) bhh[i] = i < 128 ? bch1[i] : (i < 256 ? bcat1[i - 128] : bsk1[i - 256]);
  if (i < NCATp * 128) wcat2p[i] = (i >> 7) < NCAT ? f2b(Wcat2[i]) : (unsigned short)0;
  if (i < NSKUp * 128) wsk2p[i] = (i >> 7) < NSKU ? f2b(Wsk2[i]) : (unsigned short)0;
}

// ---- l2norm both node sets -> right half of concat buffers ----
__global__ void k_l2norm_both(const float* __restrict__ xc, const float* __restrict__ xs,
                              unsigned short* __restrict__ concat_c,
                              unsigned short* __restrict__ concat_s, int Nc, int Ns) {
  int wid = (blockIdx.x * blockDim.x + threadIdx.x) >> 6;
  int lane = threadIdx.x & 63;
  const float* x;
  unsigned short* out;
  if (wid < Nc) {
    x = xc + (size_t)wid * 128;
    out = concat_c + (size_t)wid * 256 + 128;
  } else {
    int w = wid - Nc;
    if (w >= Ns) return;
    x = xs + (size_t)w * 128;
    out = concat_s + (size_t)w * 256 + 128;
  }
  const float2 v = *(const float2*)&x[lane * 2];
  float ss = waveReduceSum(v.x * v.x + v.y * v.y);
  float sc = 1.0f / fmaxf(sqrtf(ss), 1e-12f);
  out[lane * 2] = f2b(v.x * sc);
  out[lane * 2 + 1] = f2b(v.y * sc);
}

// ---- histogram over both edge sets into concatenated counters ----
__global__ void k_hist_both(const int* __restrict__ cs_dst, const int* __restrict__ sc_dst,
                            int* __restrict__ cnt, int E, int Ns) {
  int i = blockIdx.x * blockDim.x + threadIdx.x;
  if (i < E) atomicAdd(&cnt[cs_dst[i]], 1);
  else if (i < 2 * E) atomicAdd(&cnt[Ns + sc_dst[i - E]], 1);
}

// ---- exclusive scan ----
__global__ void k_scan1(const int* __restrict__ in, int* __restrict__ out,
                        int* __restrict__ partials, int nin, int nout) {
  __shared__ int sd[256];
  const int tid = threadIdx.x;
  const int base = blockIdx.x * 2048 + tid * 8;
  int v[8];
  int tsum = 0;
  #pragma unroll
  for (int u = 0; u < 8; ++u) {
    int idx = base + u;
    int t = (idx < nin) ? in[idx] : 0;
    v[u] = tsum; tsum += t;
  }
  sd[tid] = tsum;
  __syncthreads();
  for (int offp = 1; offp < 256; offp <<= 1) {
    int t = (tid >= offp) ? sd[tid - offp] : 0;
    __syncthreads();
    sd[tid] += t;
    __syncthreads();
  }
  int texcl = (tid == 0) ? 0 : sd[tid - 1];
  if (tid == 255) partials[blockIdx.x] = sd[255];
  #pragma unroll
  for (int u = 0; u < 8; ++u) {
    int idx = base + u;
    if (idx < nout) out[idx] = v[u] + texcl;
  }
}

__global__ void k_scan2(int* __restrict__ partials, int nb) {
  __shared__ int sd[256];
  const int tid = threadIdx.x;
  int v = (tid < nb) ? partials[tid] : 0;
  sd[tid] = v;
  __syncthreads();
  for (int offp = 1; offp < 256; offp <<= 1) {
    int t = (tid >= offp) ? sd[tid - offp] : 0;
    __syncthreads();
    sd[tid] += t;
    __syncthreads();
  }
  if (tid < nb) partials[tid] = (tid == 0) ? 0 : sd[tid - 1];
}

__global__ void k_scan3(int* __restrict__ out, const int* __restrict__ partials, int nout) {
  int add = partials[blockIdx.x];
  int base = blockIdx.x * 2048 + threadIdx.x * 8;
  #pragma unroll
  for (int u = 0; u < 8; ++u) {
    int idx = base + u;
    if (idx < nout) out[idx] += add;
  }
}

// ---- scatter both edge sets into one adjacency array ----
__global__ void k_scatter_both(const int* __restrict__ cs_src, const int* __restrict__ cs_dst,
                               const int* __restrict__ sc_src, const int* __restrict__ sc_dst,
                               const int* __restrict__ off, int* __restrict__ cur,
                               int* __restrict__ lst, int E, int Ns) {
  int i = blockIdx.x * blockDim.x + threadIdx.x;
  if (i >= 2 * E) return;
  int d, s;
  if (i < E) { d = cs_dst[i]; s = cs_src[i]; }
  else { d = Ns + sc_dst[i - E]; s = sc_src[i - E]; }
  int p = atomicAdd(&cur[d], 1);
  lst[off[d] + p] = s;
}

// ---- layer-1 mean aggregation, both directions ----
__global__ void k_agg128_both(const unsigned short* __restrict__ concat_c,
                              const unsigned short* __restrict__ concat_s,
                              const int* __restrict__ off, const int* __restrict__ lst,
                              unsigned short* __restrict__ out_s,
                              unsigned short* __restrict__ out_c, int Ns, int Nc) {
  int wid = (blockIdx.x * blockDim.x + threadIdx.x) >> 6;
  int lane = threadIdx.x & 63;
  const unsigned short* feat;
  unsigned short* out;
  int s, e;
  if (wid < Ns) {
    s = off[wid]; e = off[wid + 1];
    feat = concat_c; out = out_s + (size_t)wid * 256;
  } else {
    int w = wid - Ns;
    if (w >= Nc) return;
    s = off[Ns + w]; e = off[Ns + w + 1];
    feat = concat_s; out = out_c + (size_t)w * 256;
  }
  float ax = 0.f, ay = 0.f;
  for (int i = s; i < e; ++i) {
    int r = lst[i];
    unsigned v = *(const unsigned*)&feat[(size_t)r * 256 + 128 + lane * 2];
    ax += b2f((unsigned short)(v & 0xFFFF));
    ay += b2f((unsigned short)(v >> 16));
  }
  float inv = 1.0f / (float)((e - s) > 0 ? (e - s) : 1);
  out[lane * 2] = f2b(ax * inv);
  out[lane * 2 + 1] = f2b(ay * inv);
}

// ---- layer-2 mean aggregation (256-wide) ----
__global__ void k_agg_mean256(const unsigned short* __restrict__ feat,
                              const int* __restrict__ off, const int* __restrict__ lst,
                              unsigned short* __restrict__ out, int ostride, int n) {
  int wid = (blockIdx.x * blockDim.x + threadIdx.x) >> 6;
  int lane = threadIdx.x & 63;
  if (wid >= n) return;
  int s = off[wid], e = off[wid + 1];
  float a0 = 0.f, a1 = 0.f, a2 = 0.f, a3 = 0.f;
  for (int i = s; i < e; ++i) {
    int r = lst[i];
    uint2 v = *(const uint2*)&feat[(size_t)r * 256 + lane * 4];
    a0 += b2f((unsigned short)(v.x & 0xFFFF));
    a1 += b2f((unsigned short)(v.x >> 16));
    a2 += b2f((unsigned short)(v.y & 0xFFFF));
    a3 += b2f((unsigned short)(v.y >> 16));
  }
  float inv = 1.0f / (float)((e - s) > 0 ? (e - s) : 1);
  unsigned short* o = &out[(size_t)wid * ostride + lane * 4];
  o[0] = f2b(a0 * inv); o[1] = f2b(a1 * inv); o[2] = f2b(a2 * inv); o[3] = f2b(a3 * inv);
}

// ---- layer-1 GEMMs for both node types in one dispatch ----
__global__ __launch_bounds__(256) void k_gemm1_both(
    const unsigned short* __restrict__ As_g, const unsigned short* __restrict__ Ws_g,
    const float* __restrict__ bs_g, unsigned short* __restrict__ Cs_g, int Ms, int NTs2,
    const unsigned short* __restrict__ Ac_g, const unsigned short* __restrict__ Wc_g,
    const float* __restrict__ bc_g, unsigned short* __restrict__ Cc_g, int Mc) {
  __shared__ __align__(16) unsigned short As[4096];
  __shared__ __align__(16) unsigned short Bs[4096];
  const int nwg = gridDim.x, orig = blockIdx.x;
  const int q8 = nwg >> 3, r8 = nwg & 7;
  const int xcd = orig & 7, cidx = orig >> 3;
  int wg = (xcd < r8 ? xcd * (q8 + 1) : r8 * (q8 + 1) + (xcd - r8) * q8) + cidx;

  const unsigned short *A, *W;
  const float* bias;
  unsigned short* C;
  int M, ldc;
  if (wg < NTs2) { A = As_g; W = Ws_g; bias = bs_g; C = Cs_g; M = Ms; ldc = 256; }
  else { wg -= NTs2; A = Ac_g; W = Wc_g; bias = bc_g; C = Cc_g; M = Mc; ldc = 512; }
  const int bm = (wg >> 1) * 128, bn = (wg & 1) * 128;

  const int tid = threadIdx.x, lane = tid & 63, wave = tid >> 6;
  const int wm = (wave >> 1) << 6, wn = (wave & 1) << 6;
  const int l15 = lane & 15, l4 = lane >> 4;

  f32x4 acc[4][4] = {};
  for (int k0 = 0; k0 < 256; k0 += 32) {
    stage_tile(A + (size_t)bm * 256 + k0, 256, As, wave, lane);
    stage_tile(W + (size_t)bn * 256 + k0, 256, Bs, wave, lane);
    __syncthreads();
    bf16x8 af[4], bfr[4];
    #pragma unroll
    for (int i = 0; i < 4; ++i) {
      af[i] = read_frag32(As, wm + i * 16 + l15, l4);
      bfr[i] = read_frag32(Bs, wn + i * 16 + l15, l4);
    }
    #pragma unroll
    for (int i = 0; i < 4; ++i)
      #pragma unroll
      for (int j = 0; j < 4; ++j)
        acc[i][j] = __builtin_amdgcn_mfma_f32_16x16x32_bf16(af[i], bfr[j], acc[i][j], 0, 0, 0);
    __syncthreads();
  }
  #pragma unroll
  for (int j = 0; j < 4; ++j) {
    int col = bn + wn + j * 16 + l15;
    float bj = bias[col];
    #pragma unroll
    for (int i = 0; i < 4; ++i) {
      int r0 = bm + wm + i * 16 + (l4 << 2);
      #pragma unroll
      for (int q = 0; q < 4; ++q) {
        int row = r0 + q;
        if (row < M) C[(size_t)row * ldc + col] = f2b(fmaxf(acc[i][j][q] + bj, 0.0f));
      }
    }
  }
}

// ---- k_embhid: emb = concat2 @ W2^T + b2 -> out_emb fp32 + embT (LDS);
//      then 3 hidden chunks h = relu(embT @ Whh^T + bhh) -> hidden[Ncp][384] bf16
__global__ __launch_bounds__(256) void k_embhid(
    const unsigned short* __restrict__ A2, const unsigned short* __restrict__ W2,
    const float* __restrict__ b2,
    const unsigned short* __restrict__ Whh, const float* __restrict__ bhh,
    float* __restrict__ out_emb, unsigned short* __restrict__ hidden, int M) {
  __shared__ __align__(16) unsigned short As[4096];
  __shared__ __align__(16) unsigned short Bs[4096];
  __shared__ __align__(16) unsigned short embT[16384];

  const int bm = blockIdx.x * 128;
  const int tid = threadIdx.x, lane = tid & 63, wave = tid >> 6;
  const int wm = (wave >> 1) << 6, wn = (wave & 1) << 6;
  const int l15 = lane & 15, l4 = lane >> 4;

  {  // emb
    f32x4 acc[4][4] = {};
    for (int k0 = 0; k0 < 512; k0 += 32) {
      stage_tile(A2 + (size_t)bm * 512 + k0, 512, As, wave, lane);
      stage_tile(W2 + k0, 512, Bs, wave, lane);
      __syncthreads();
      bf16x8 af[4], bfr[4];
      #pragma unroll
      for (int i = 0; i < 4; ++i) {
        af[i] = read_frag32(As, wm + i * 16 + l15, l4);
        bfr[i] = read_frag32(Bs, wn + i * 16 + l15, l4);
      }
      #pragma unroll
      for (int i = 0; i < 4; ++i)
        #pragma unroll
        for (int j = 0; j < 4; ++j)
          acc[i][j] = __builtin_amdgcn_mfma_f32_16x16x32_bf16(af[i], bfr[j], acc[i][j], 0, 0, 0);
      __syncthreads();
    }
    #pragma unroll
    for (int j = 0; j < 4; ++j) {
      int col = wn + j * 16 + l15;
      float bj = b2[col];
      #pragma unroll
      for (int i = 0; i < 4; ++i) {
        int r0 = wm + i * 16 + (l4 << 2);
        #pragma unroll
        for (int q = 0; q < 4; ++q) {
          float v = acc[i][j][q] + bj;
          int rl = r0 + q;
          if (bm + rl < M) out_emb[(size_t)(bm + rl) * 128 + col] = v;
          write_elem128(embT, rl, col, f2b(v));
        }
      }
    }
  }
  __syncthreads();

  for (int hc = 0; hc < 3; ++hc) {
    f32x4 hacc[4][4] = {};
    for (int k0 = 0; k0 < 128; k0 += 32) {
      stage_tile(Whh + (size_t)hc * 128 * 128 + k0, 128, Bs, wave, lane);
      __syncthreads();
      bf16x8 af[4], bfr[4];
      const int kslot = (k0 >> 3) + l4;
      #pragma unroll
      for (int i = 0; i < 4; ++i) {
        af[i] = read_frag128(embT, wm + i * 16 + l15, kslot);
        bfr[i] = read_frag32(Bs, wn + i * 16 + l15, l4);
      }
      #pragma unroll
      for (int i = 0; i < 4; ++i)
        #pragma unroll
        for (int j = 0; j < 4; ++j)
          hacc[i][j] = __builtin_amdgcn_mfma_f32_16x16x32_bf16(af[i], bfr[j], hacc[i][j], 0, 0, 0);
      __syncthreads();
    }
    #pragma unroll
    for (int j = 0; j < 4; ++j) {
      int col = wn + j * 16 + l15;
      float bj = bhh[hc * 128 + col];
      #pragma unroll
      for (int i = 0; i < 4; ++i) {
        int r0 = wm + i * 16 + (l4 << 2);
        #pragma unroll
        for (int q = 0; q < 4; ++q) {
          hidden[(size_t)(bm + r0 + q) * 384 + hc * 128 + col] =
              f2b(fmaxf(hacc[i][j][q] + bj, 0.0f));
        }
      }
    }
  }
}

// ---- k_heads: one 128x128 output tile per block (cat: 2 chunks, sku: 8) ----
// transposed: A = W_head chunk, B = hidden slice -> float4 stores along head dim
__global__ __launch_bounds__(256) void k_heads(
    const unsigned short* __restrict__ hidden,
    const unsigned short* __restrict__ Wcat, const float* __restrict__ bcat, int NCAT,
    int ncat_ch,
    const unsigned short* __restrict__ Wsku, const float* __restrict__ bsku, int NSKU,
    int nsku_ch,
    float* __restrict__ out_cat, float* __restrict__ out_sku, int M) {
  __shared__ __align__(16) unsigned short Aw[16384];  // W chunk [128][128]
  __shared__ __align__(16) unsigned short Bh[16384];  // hidden tile [128][128]

  const int nwg = gridDim.x, orig = blockIdx.x;
  const int q8 = nwg >> 3, r8 = nwg & 7;
  const int xcd = orig & 7, cidx = orig >> 3;
  const int wg = (xcd < r8 ? xcd * (q8 + 1) : r8 * (q8 + 1) + (xcd - r8) * q8) + cidx;

  const int nch = ncat_ch + nsku_ch;
  const int bt = wg / nch;
  const int c = wg % nch;
  const int bm = bt * 128;

  const unsigned short* Wh;
  const float* bh;
  float* oh;
  int Nh, cc, hoff;
  if (c < ncat_ch) { Wh = Wcat; bh = bcat; oh = out_cat; Nh = NCAT; cc = c; hoff = 128; }
  else { Wh = Wsku; bh = bsku; oh = out_sku; Nh = NSKU; cc = c - ncat_ch; hoff = 256; }

  const int tid = threadIdx.x, lane = tid & 63, wave = tid >> 6;
  const int wm = (wave >> 1) << 6, wn = (wave & 1) << 6;
  const int l15 = lane & 15, l4 = lane >> 4;

  stage_tile128(Wh + (size_t)cc * 128 * 128, 128, Aw, wave, lane);
  stage_tile128(hidden + (size_t)bm * 384 + hoff, 384, Bh, wave, lane);
  __syncthreads();

  f32x4 acc[4][4] = {};
  #pragma unroll
  for (int ks = 0; ks < 4; ++ks) {
    bf16x8 af[4], bfr[4];
    #pragma unroll
    for (int i = 0; i < 4; ++i) {
      af[i] = read_frag128(Aw, wm + i * 16 + l15, ks * 4 + l4);
      bfr[i] = read_frag128(Bh, wn + i * 16 + l15, ks * 4 + l4);
    }
    #pragma unroll
    for (int i = 0; i < 4; ++i)
      #pragma unroll
      for (int j = 0; j < 4; ++j)
        acc[i][j] = __builtin_amdgcn_mfma_f32_16x16x32_bf16(af[i], bfr[j], acc[i][j], 0, 0, 0);
  }

  // transposed epilogue: D[a=headcol][b=client row]
  #pragma unroll
  for (int i = 0; i < 4; ++i) {
    const int n0 = cc * 128 + wm + i * 16 + (l4 << 2);
    if (n0 < Nh) {  // Nh % 4 == 0 -> whole quad valid
      const float4 bv = *(const float4*)&bh[n0];
      #pragma unroll
      for (int j = 0; j < 4; ++j) {
        const int m = wn + j * 16 + l15;
        if (bm + m < M) {
          float4 ov;
          ov.x = sigmoidf_(acc[i][j][0] + bv.x);
          ov.y = sigmoidf_(acc[i][j][1] + bv.y);
          ov.z = sigmoidf_(acc[i][j][2] + bv.z);
          ov.w = sigmoidf_(acc[i][j][3] + bv.w);
          *(float4*)&oh[(size_t)(bm + m) * Nh + n0] = ov;
        }
      }
    }
  }
}

// ---- churn head: dot(hidden[:,0:128], w) + b -> sigmoid, one wave per row ----
__global__ void k_churn(const unsigned short* __restrict__ hid,
                        const float* __restrict__ w, const float* __restrict__ b,
                        float* __restrict__ out, int n) {
  int wid = (blockIdx.x * blockDim.x + threadIdx.x) >> 6;
  int lane = threadIdx.x & 63;
  if (wid >= n) return;
  unsigned v = *(const unsigned*)&hid[(size_t)wid * 384 + lane * 2];
  const float2 ww = *(const float2*)&w[lane * 2];
  float sum = waveReduceSum(b2f((unsigned short)(v & 0xFFFF)) * ww.x +
                            b2f((unsigned short)(v >> 16)) * ww.y);
  if (lane == 0) out[wid] = sigmoidf_(sum + b[0]);
}

extern "C" void kernel_launch(void* const* d_in, const int* in_sizes, int n_in,
                              void* d_out, int out_size, void* d_ws, size_t ws_size,
                              hipStream_t stream) {
  const float* x_client = (const float*)d_in[0];
  const float* x_sku    = (const float*)d_in[1];
  const int* cs_src = (const int*)d_in[2];
  const int* cs_dst = (const int*)d_in[3];
  const int* sc_src = (const int*)d_in[4];
  const int* sc_dst = (const int*)d_in[5];
  const float* W1l_cs = (const float*)d_in[6];
  const float* b1_cs  = (const float*)d_in[7];
  const float* W1r_cs = (const float*)d_in[8];
  const float* W1l_sc = (const float*)d_in[9];
  const float* b1_sc  = (const float*)d_in[10];
  const float* W1r_sc = (const float*)d_in[11];
  const float* Wlin1_c = (const float*)d_in[12];
  const float* blin1_c = (const float*)d_in[13];
  const float* Wlin1_s = (const float*)d_in[14];
  const float* blin1_s = (const float*)d_in[15];
  const float* W2l_sc = (const float*)d_in[19];
  const float* b2_sc  = (const float*)d_in[20];
  const float* W2r_sc = (const float*)d_in[21];
  const float* Wlin2_c = (const float*)d_in[22];
  const float* blin2_c = (const float*)d_in[23];
  const float* Wch1 = (const float*)d_in[26];
  const float* bch1 = (const float*)d_in[27];
  const float* Wch2 = (const float*)d_in[28];
  const float* bch2 = (const float*)d_in[29];
  const float* Wcat1 = (const float*)d_in[30];
  const float* bcat1 = (const float*)d_in[31];
  const float* Wcat2 = (const float*)d_in[32];
  const float* bcat2 = (const float*)d_in[33];
  const float* Wsk1 = (const float*)d_in[34];
  const float* bsk1 = (const float*)d_in[35];
  const float* Wsk2 = (const float*)d_in[36];
  const float* bsk2 = (const float*)d_in[37];

  const int D = 128;
  const int Nc = in_sizes[0] / D;
  const int Ns = in_sizes[1] / D;
  const int E  = in_sizes[2];
  const int NCAT = in_sizes[33];
  const int NSKU = in_sizes[37];

  const int NTc = (Nc + 127) / 128;
  const int NTs = (Ns + 127) / 128;
  const int Ncp = NTc * 128;
  const int Nsp = NTs * 128;
  const int NCATp = ((NCAT + 127) / 128) * 128;
  const int NSKUp = ((NSKU + 127) / 128) * 128;
  const int ncat_ch = NCATp / 128, nsku_ch = NSKUp / 128;

  // ---- workspace layout ----
  char* wsb = (char*)d_ws;
  size_t o = 0;
  auto alloc = [&](size_t bytes) -> char* {
    char* p = wsb + o;
    o = (o + bytes + 255) & ~(size_t)255;
    return p;
  };
  unsigned short* concat_s = (unsigned short*)alloc((size_t)Nsp * 256 * 2);
  unsigned short* concat_c = (unsigned short*)alloc((size_t)Ncp * 256 * 2);
  unsigned short* h1_s     = (unsigned short*)alloc((size_t)Nsp * 256 * 2);
  unsigned short* big      = (unsigned short*)alloc((size_t)Ncp * 512 * 2);  // concat2
  unsigned short* hidden   = (unsigned short*)alloc((size_t)Ncp * 384 * 2);
  unsigned short* wc1s = (unsigned short*)alloc(256 * 256 * 2);
  float* bc1s = (float*)alloc(256 * 4);
  unsigned short* wc1c = (unsigned short*)alloc(256 * 256 * 2);
  float* bc1c = (float*)alloc(256 * 4);
  unsigned short* wc2c = (unsigned short*)alloc(128 * 512 * 2);
  float* bc2c = (float*)alloc(128 * 4);
  unsigned short* whh  = (unsigned short*)alloc(384 * 128 * 2);
  float* bhh  = (float*)alloc(384 * 4);
  unsigned short* wcat2p = (unsigned short*)alloc((size_t)NCATp * 128 * 2);
  unsigned short* wsk2p  = (unsigned short*)alloc((size_t)NSKUp * 128 * 2);
  int* off   = (int*)alloc((size_t)(Ns + Nc + 1) * 4);
  int* zbase = (int*)alloc((size_t)(2 * (Ns + Nc)) * 4);
  int* cnt = zbase;
  int* cur = zbase + (Ns + Nc);
  int* lst = (int*)alloc((size_t)(2 * E) * 4);
  int* partials = (int*)alloc(1024 * 4);

  float* out_churn = (float*)d_out;
  float* out_cat = out_churn + (size_t)Nc;
  float* out_sku = out_cat + (size_t)Nc * NCAT;
  float* out_emb = out_sku + (size_t)Nc * NSKU;

  hipMemsetAsync(zbase, 0, (size_t)(2 * (Ns + Nc)) * 4, stream);

  // 1. weight prep
  k_prep_all<<<512, 256, 0, stream>>>(
      W1l_cs, W1r_cs, Wlin1_s, b1_cs, blin1_s,
      W1l_sc, W1r_sc, Wlin1_c, b1_sc, blin1_c,
      W2l_sc, W2r_sc, Wlin2_c, b2_sc, blin2_c,
      Wch1, bch1, Wcat1, bcat1, Wsk1, bsk1, Wcat2, Wsk2,
      wc1s, bc1s, wc1c, bc1c, wc2c, bc2c, whh, bhh, wcat2p, wsk2p,
      NCAT, NCATp, NSKU, NSKUp);

  // 2. l2norm both
  k_l2norm_both<<<(Nc + Ns + 3) / 4, 256, 0, stream>>>(
      x_client, x_sku, concat_c, concat_s, Nc, Ns);

  // 3-7. CSR build (concatenated)
  const int n_nodes = Ns + Nc;
  k_hist_both<<<(2 * E + 255) / 256, 256, 0, stream>>>(cs_dst, sc_dst, cnt, E, Ns);
  const int nb = (n_nodes + 1 + 2047) / 2048;
  k_scan1<<<nb, 256, 0, stream>>>(cnt, off, partials, n_nodes, n_nodes + 1);
  k_scan2<<<1, 256, 0, stream>>>(partials, nb);
  k_scan3<<<nb, 256, 0, stream>>>(off, partials, n_nodes + 1);
  k_scatter_both<<<(2 * E + 255) / 256, 256, 0, stream>>>(
      cs_src, cs_dst, sc_src, sc_dst, off, cur, lst, E, Ns);

  // 8. layer-1 aggregation
  k_agg128_both<<<(n_nodes + 3) / 4, 256, 0, stream>>>(
      concat_c, concat_s, off, lst, concat_s, concat_c, Ns, Nc);

  // 9. layer-1 GEMMs
  k_gemm1_both<<<NTs * 2 + NTc * 2, 256, 0, stream>>>(
      concat_s, wc1s, bc1s, h1_s, Ns, NTs * 2,
      concat_c, wc1c, bc1c, big + 256, Nc);

  // 10. layer-2 aggregation (client destinations)
  k_agg_mean256<<<(Nc + 3) / 4, 256, 0, stream>>>(h1_s, off + Ns, lst, big, 512, Nc);

  // 11. emb + hidden
  k_embhid<<<NTc, 256, 0, stream>>>(big, wc2c, bc2c, whh, bhh, out_emb, hidden, Nc);

  // 12-13. heads
  k_heads<<<NTc * (ncat_ch + nsku_ch), 256, 0, stream>>>(
      hidden, wcat2p, bcat2, NCAT, ncat_ch, wsk2p, bsk2, NSKU, nsku_ch,
      out_cat, out_sku, Nc);
  k_churn<<<(Nc + 3) / 4, 256, 0, stream>>>(hidden, Wch2, bch2, out_churn, Nc);
}

// Round 5
// 646.860 us; speedup vs baseline: 2.2663x; 1.0673x over previous
//
#include <hip/hip_runtime.h>
#include <hip/hip_bf16.h>
#include <cstdint>

// ---------------------------------------------------------------------------
// FullModel: hetero-GraphSAGE (2 layers) + 3 MLP heads.
// R5: dispatch fusion (16 -> 10), 2-phase pipelined MFMA staging (T3-min:
// stage next K-tile before current MFMAs, one barrier/step, dbuf LDS),
// depth-2 unrolled gather loops in aggregations.
//   k_front:  weight prep + l2norm(both) + edge histogram(both)
//   scan1/2/3, scatter_both (concatenated CSR)
//   k_agg128_both, k_gemm1_both (pipelined), k_agg_mean256,
//   k_embhid (pipelined; emb + 3 hidden chunks), k_heads (+churn role)
// All GEMMs: mfma_f32_16x16x32_bf16, fp32 acc, global_load_lds(16B),
// both-sides XOR swizzle (G21).
// ---------------------------------------------------------------------------

typedef __attribute__((ext_vector_type(8))) short bf16x8;
typedef __attribute__((ext_vector_type(4))) float f32x4;

__device__ __forceinline__ float b2f(unsigned short u) {
  return __uint_as_float(((unsigned)u) << 16);
}
__device__ __forceinline__ unsigned short f2b(float f) {
  unsigned u = __float_as_uint(f);
  return (unsigned short)((u + 0x7FFFu + ((u >> 16) & 1u)) >> 16);
}
__device__ __forceinline__ float sigmoidf_(float v) {
  return 1.0f / (1.0f + __expf(-v));
}

__device__ __forceinline__ float waveReduceSum(float v) {
  #pragma unroll
  for (int s = 32; s > 0; s >>= 1) v += __shfl_xor(v, s, 64);
  return v;
}

__device__ __forceinline__ void gload16(const void* g, void* l) {
  __builtin_amdgcn_global_load_lds(
      (const __attribute__((address_space(1))) unsigned int*)g,
      (__attribute__((address_space(3))) unsigned int*)l, 16, 0, 0);
}

// stage a [128 rows][32 k] bf16 tile (linear LDS dest, pre-swizzled source)
__device__ __forceinline__ void stage_tile(const unsigned short* __restrict__ G,
                                           int ld, unsigned short* lds,
                                           int wave, int lane) {
  #pragma unroll
  for (int j = 0; j < 2; ++j) {
    const int p = wave * 128 + j * 64 + lane;
    const int rr = p >> 2;
    const int sl = (p & 3) ^ (rr & 3);
    gload16(G + (size_t)rr * ld + (sl << 3), lds + ((wave * 128 + j * 64) << 3));
  }
}

// stage a [128 rows][128 k] bf16 tile (2048 16B-slots, 8 per thread)
__device__ __forceinline__ void stage_tile128(const unsigned short* __restrict__ G,
                                              int ldg, unsigned short* lds,
                                              int wave, int lane) {
  #pragma unroll
  for (int u = 0; u < 8; ++u) {
    const int base = u * 256 + wave * 64;
    const int p = base + lane;
    const int row = p >> 4;
    const int sl = (p & 15) ^ (row & 7);
    gload16(G + (size_t)row * ldg + (sl << 3), lds + (base << 3));
  }
}

// read an 8-elem bf16 fragment from a staged [rows][32] tile
__device__ __forceinline__ bf16x8 read_frag32(const unsigned short* lds, int row, int kg) {
  const int srd = kg ^ (row & 3);
  return *(const bf16x8*)&lds[row * 32 + (srd << 3)];
}

// [128][128] bf16 LDS tile, 16B-slot swizzle: phys = logical ^ (row&7)
__device__ __forceinline__ bf16x8 read_frag128(const unsigned short* lds, int row, int kslot) {
  const int ps = kslot ^ (row & 7);
  return *(const bf16x8*)&lds[row * 128 + (ps << 3)];
}
__device__ __forceinline__ void write_elem128(unsigned short* lds, int row, int col,
                                              unsigned short v) {
  const int slot = (col >> 3) ^ (row & 7);
  lds[row * 128 + (slot << 3) + (col & 7)] = v;
}

// ---- k_front: weight prep (blocks [0,512)) + l2norm (next nl2 blocks)
//      + histogram (next nhist blocks) ----
__global__ void k_front(
    // prep inputs
    const float* __restrict__ W1l_cs, const float* __restrict__ W1r_cs,
    const float* __restrict__ Wlin1_s, const float* __restrict__ b1_cs,
    const float* __restrict__ blin1_s,
    const float* __restrict__ W1l_sc, const float* __restrict__ W1r_sc,
    const float* __restrict__ Wlin1_c, const float* __restrict__ b1_sc,
    const float* __restrict__ blin1_c,
    const float* __restrict__ W2l_sc, const float* __restrict__ W2r_sc,
    const float* __restrict__ Wlin2_c, const float* __restrict__ b2_sc,
    const float* __restrict__ blin2_c,
    const float* __restrict__ Wch1, const float* __restrict__ bch1,
    const float* __restrict__ Wcat1, const float* __restrict__ bcat1,
    const float* __restrict__ Wsk1, const float* __restrict__ bsk1,
    const float* __restrict__ Wcat2, const float* __restrict__ Wsk2,
    unsigned short* __restrict__ wc1s, float* __restrict__ bc1s,
    unsigned short* __restrict__ wc1c, float* __restrict__ bc1c,
    unsigned short* __restrict__ wc2c, float* __restrict__ bc2c,
    unsigned short* __restrict__ whh, float* __restrict__ bhh,
    unsigned short* __restrict__ wcat2p, unsigned short* __restrict__ wsk2p,
    int NCAT, int NCATp, int NSKU, int NSKUp,
    // l2norm inputs
    const float* __restrict__ xc, const float* __restrict__ xs,
    unsigned short* __restrict__ concat_c, unsigned short* __restrict__ concat_s,
    int Nc, int Ns, int nl2,
    // hist inputs
    const int* __restrict__ cs_dst, const int* __restrict__ sc_dst,
    int* __restrict__ cnt, int E) {
  const int blk = blockIdx.x;
  if (blk < 512) {
    const int i = blk * 256 + threadIdx.x;
    if (i < 65536) {
      {
        int n = i >> 8, k = i & 255;
        wc1s[i] = f2b(k < 128 ? W1l_cs[n * 128 + k]
                              : W1r_cs[n * 128 + k - 128] + Wlin1_s[n * 128 + k - 128]);
        wc1c[i] = f2b(k < 128 ? W1l_sc[n * 128 + k]
                              : W1r_sc[n * 128 + k - 128] + Wlin1_c[n * 128 + k - 128]);
      }
      {
        int n = i >> 9, k = i & 511;
        wc2c[i] = f2b(k < 256 ? W2l_sc[n * 256 + k]
                              : W2r_sc[n * 256 + k - 256] + Wlin2_c[n * 256 + k - 256]);
      }
    }
    if (i < 256) { bc1s[i] = b1_cs[i] + blin1_s[i]; bc1c[i] = b1_sc[i] + blin1_c[i]; }
    if (i < 128) bc2c[i] = b2_sc[i] + blin2_c[i];
    if (i < 384 * 128) {
      int n = i >> 7, k = i & 127;
      const float* w = n < 128 ? Wch1 : (n < 256 ? Wcat1 : Wsk1);
      whh[i] = f2b(w[(n & 127) * 128 + k]);
    }
    if (i < 384) bhh[i] = i < 128 ? bch1[i] : (i < 256 ? bcat1[i - 128] : bsk1[i - 256]);
    if (i < NCATp * 128) wcat2p[i] = (i >> 7) < NCAT ? f2b(Wcat2[i]) : (unsigned short)0;
    if (i < NSKUp * 128) wsk2p[i] = (i >> 7) < NSKU ? f2b(Wsk2[i]) : (unsigned short)0;
  } else if (blk < 512 + nl2) {
    const int wid = (blk - 512) * 4 + (threadIdx.x >> 6);
    const int lane = threadIdx.x & 63;
    const float* x;
    unsigned short* out;
    if (wid < Nc) {
      x = xc + (size_t)wid * 128;
      out = concat_c + (size_t)wid * 256 + 128;
    } else {
      int w = wid - Nc;
      if (w >= Ns) return;
      x = xs + (size_t)w * 128;
      out = concat_s + (size_t)w * 256 + 128;
    }
    const float2 v = *(const float2*)&x[lane * 2];
    float ss = waveReduceSum(v.x * v.x + v.y * v.y);
    float sc = 1.0f / fmaxf(sqrtf(ss), 1e-12f);
    out[lane * 2] = f2b(v.x * sc);
    out[lane * 2 + 1] = f2b(v.y * sc);
  } else {
    const int i = (blk - 512 - nl2) * 256 + threadIdx.x;
    if (i < E) atomicAdd(&cnt[cs_dst[i]], 1);
    else if (i < 2 * E) atomicAdd(&cnt[Ns + sc_dst[i - E]], 1);
  }
}

// ---- exclusive scan ----
__global__ void k_scan1(const int* __restrict__ in, int* __restrict__ out,
                        int* __restrict__ partials, int nin, int nout) {
  __shared__ int sd[256];
  const int tid = threadIdx.x;
  const int base = blockIdx.x * 2048 + tid * 8;
  int v[8];
  int tsum = 0;
  #pragma unroll
  for (int u = 0; u < 8; ++u) {
    int idx = base + u;
    int t = (idx < nin) ? in[idx] : 0;
    v[u] = tsum; tsum += t;
  }
  sd[tid] = tsum;
  __syncthreads();
  for (int offp = 1; offp < 256; offp <<= 1) {
    int t = (tid >= offp) ? sd[tid - offp] : 0;
    __syncthreads();
    sd[tid] += t;
    __syncthreads();
  }
  int texcl = (tid == 0) ? 0 : sd[tid - 1];
  if (tid == 255) partials[blockIdx.x] = sd[255];
  #pragma unroll
  for (int u = 0; u < 8; ++u) {
    int idx = base + u;
    if (idx < nout) out[idx] = v[u] + texcl;
  }
}

__global__ void k_scan2(int* __restrict__ partials, int nb) {
  __shared__ int sd[256];
  const int tid = threadIdx.x;
  int v = (tid < nb) ? partials[tid] : 0;
  sd[tid] = v;
  __syncthreads();
  for (int offp = 1; offp < 256; offp <<= 1) {
    int t = (tid >= offp) ? sd[tid - offp] : 0;
    __syncthreads();
    sd[tid] += t;
    __syncthreads();
  }
  if (tid < nb) partials[tid] = (tid == 0) ? 0 : sd[tid - 1];
}

__global__ void k_scan3(int* __restrict__ out, const int* __restrict__ partials, int nout) {
  int add = partials[blockIdx.x];
  int base = blockIdx.x * 2048 + threadIdx.x * 8;
  #pragma unroll
  for (int u = 0; u < 8; ++u) {
    int idx = base + u;
    if (idx < nout) out[idx] += add;
  }
}

// ---- scatter both edge sets into one adjacency array ----
__global__ void k_scatter_both(const int* __restrict__ cs_src, const int* __restrict__ cs_dst,
                               const int* __restrict__ sc_src, const int* __restrict__ sc_dst,
                               const int* __restrict__ off, int* __restrict__ cur,
                               int* __restrict__ lst, int E, int Ns) {
  int i = blockIdx.x * blockDim.x + threadIdx.x;
  if (i >= 2 * E) return;
  int d, s;
  if (i < E) { d = cs_dst[i]; s = cs_src[i]; }
  else { d = Ns + sc_dst[i - E]; s = sc_src[i - E]; }
  int p = atomicAdd(&cur[d], 1);
  lst[off[d] + p] = s;
}

// ---- layer-1 mean aggregation, both directions, depth-2 unrolled ----
__global__ void k_agg128_both(const unsigned short* __restrict__ concat_c,
                              const unsigned short* __restrict__ concat_s,
                              const int* __restrict__ off, const int* __restrict__ lst,
                              unsigned short* __restrict__ out_s,
                              unsigned short* __restrict__ out_c, int Ns, int Nc) {
  int wid = (blockIdx.x * blockDim.x + threadIdx.x) >> 6;
  int lane = threadIdx.x & 63;
  const unsigned short* feat;
  unsigned short* out;
  int s, e;
  if (wid < Ns) {
    s = off[wid]; e = off[wid + 1];
    feat = concat_c; out = out_s + (size_t)wid * 256;
  } else {
    int w = wid - Ns;
    if (w >= Nc) return;
    s = off[Ns + w]; e = off[Ns + w + 1];
    feat = concat_s; out = out_c + (size_t)w * 256;
  }
  float ax0 = 0.f, ay0 = 0.f, ax1 = 0.f, ay1 = 0.f;
  int i = s;
  for (; i + 2 <= e; i += 2) {
    int r0 = lst[i], r1 = lst[i + 1];
    unsigned v0 = *(const unsigned*)&feat[(size_t)r0 * 256 + 128 + lane * 2];
    unsigned v1 = *(const unsigned*)&feat[(size_t)r1 * 256 + 128 + lane * 2];
    ax0 += b2f((unsigned short)(v0 & 0xFFFF));
    ay0 += b2f((unsigned short)(v0 >> 16));
    ax1 += b2f((unsigned short)(v1 & 0xFFFF));
    ay1 += b2f((unsigned short)(v1 >> 16));
  }
  if (i < e) {
    int r0 = lst[i];
    unsigned v0 = *(const unsigned*)&feat[(size_t)r0 * 256 + 128 + lane * 2];
    ax0 += b2f((unsigned short)(v0 & 0xFFFF));
    ay0 += b2f((unsigned short)(v0 >> 16));
  }
  float inv = 1.0f / (float)((e - s) > 0 ? (e - s) : 1);
  out[lane * 2] = f2b((ax0 + ax1) * inv);
  out[lane * 2 + 1] = f2b((ay0 + ay1) * inv);
}

// ---- layer-2 mean aggregation (256-wide), depth-2 unrolled ----
__global__ void k_agg_mean256(const unsigned short* __restrict__ feat,
                              const int* __restrict__ off, const int* __restrict__ lst,
                              unsigned short* __restrict__ out, int ostride, int n) {
  int wid = (blockIdx.x * blockDim.x + threadIdx.x) >> 6;
  int lane = threadIdx.x & 63;
  if (wid >= n) return;
  int s = off[wid], e = off[wid + 1];
  float a0 = 0.f, a1 = 0.f, a2 = 0.f, a3 = 0.f;
  float b0 = 0.f, b1 = 0.f, b2_ = 0.f, b3 = 0.f;
  int i = s;
  for (; i + 2 <= e; i += 2) {
    int r0 = lst[i], r1 = lst[i + 1];
    uint2 v0 = *(const uint2*)&feat[(size_t)r0 * 256 + lane * 4];
    uint2 v1 = *(const uint2*)&feat[(size_t)r1 * 256 + lane * 4];
    a0 += b2f((unsigned short)(v0.x & 0xFFFF));
    a1 += b2f((unsigned short)(v0.x >> 16));
    a2 += b2f((unsigned short)(v0.y & 0xFFFF));
    a3 += b2f((unsigned short)(v0.y >> 16));
    b0 += b2f((unsigned short)(v1.x & 0xFFFF));
    b1 += b2f((unsigned short)(v1.x >> 16));
    b2_ += b2f((unsigned short)(v1.y & 0xFFFF));
    b3 += b2f((unsigned short)(v1.y >> 16));
  }
  if (i < e) {
    int r0 = lst[i];
    uint2 v0 = *(const uint2*)&feat[(size_t)r0 * 256 + lane * 4];
    a0 += b2f((unsigned short)(v0.x & 0xFFFF));
    a1 += b2f((unsigned short)(v0.x >> 16));
    a2 += b2f((unsigned short)(v0.y & 0xFFFF));
    a3 += b2f((unsigned short)(v0.y >> 16));
  }
  float inv = 1.0f / (float)((e - s) > 0 ? (e - s) : 1);
  unsigned short* o = &out[(size_t)wid * ostride + lane * 4];
  o[0] = f2b((a0 + b0) * inv); o[1] = f2b((a1 + b1) * inv);
  o[2] = f2b((a2 + b2_) * inv); o[3] = f2b((a3 + b3) * inv);
}

// ---- layer-1 GEMMs, both node types, 2-phase pipelined staging ----
__global__ __launch_bounds__(256) void k_gemm1_both(
    const unsigned short* __restrict__ As_g, const unsigned short* __restrict__ Ws_g,
    const float* __restrict__ bs_g, unsigned short* __restrict__ Cs_g, int Ms, int NTs2,
    const unsigned short* __restrict__ Ac_g, const unsigned short* __restrict__ Wc_g,
    const float* __restrict__ bc_g, unsigned short* __restrict__ Cc_g, int Mc) {
  __shared__ __align__(16) unsigned short As[8192];  // dbuf 2x4096
  __shared__ __align__(16) unsigned short Bs[8192];
  const int nwg = gridDim.x, orig = blockIdx.x;
  const int q8 = nwg >> 3, r8 = nwg & 7;
  const int xcd = orig & 7, cidx = orig >> 3;
  int wg = (xcd < r8 ? xcd * (q8 + 1) : r8 * (q8 + 1) + (xcd - r8) * q8) + cidx;

  const unsigned short *A, *W;
  const float* bias;
  unsigned short* C;
  int M, ldc;
  if (wg < NTs2) { A = As_g; W = Ws_g; bias = bs_g; C = Cs_g; M = Ms; ldc = 256; }
  else { wg -= NTs2; A = Ac_g; W = Wc_g; bias = bc_g; C = Cc_g; M = Mc; ldc = 512; }
  const int bm = (wg >> 1) * 128, bn = (wg & 1) * 128;

  const int tid = threadIdx.x, lane = tid & 63, wave = tid >> 6;
  const int wm = (wave >> 1) << 6, wn = (wave & 1) << 6;
  const int l15 = lane & 15, l4 = lane >> 4;

  const unsigned short* Abase = A + (size_t)bm * 256;
  const unsigned short* Wbase = W + (size_t)bn * 256;

  f32x4 acc[4][4] = {};
  stage_tile(Abase, 256, As, wave, lane);
  stage_tile(Wbase, 256, Bs, wave, lane);
  __syncthreads();
  int cur = 0;
  for (int t = 0; t < 8; ++t) {
    if (t < 7) {
      stage_tile(Abase + (t + 1) * 32, 256, As + ((cur ^ 1) << 12), wave, lane);
      stage_tile(Wbase + (t + 1) * 32, 256, Bs + ((cur ^ 1) << 12), wave, lane);
    }
    const unsigned short* Ac = As + (cur << 12);
    const unsigned short* Bc = Bs + (cur << 12);
    bf16x8 af[4], bfr[4];
    #pragma unroll
    for (int i = 0; i < 4; ++i) {
      af[i] = read_frag32(Ac, wm + i * 16 + l15, l4);
      bfr[i] = read_frag32(Bc, wn + i * 16 + l15, l4);
    }
    #pragma unroll
    for (int i = 0; i < 4; ++i)
      #pragma unroll
      for (int j = 0; j < 4; ++j)
        acc[i][j] = __builtin_amdgcn_mfma_f32_16x16x32_bf16(af[i], bfr[j], acc[i][j], 0, 0, 0);
    __syncthreads();  // drains next-stage loads; protects cur buffer reuse
    cur ^= 1;
  }
  #pragma unroll
  for (int j = 0; j < 4; ++j) {
    int col = bn + wn + j * 16 + l15;
    float bj = bias[col];
    #pragma unroll
    for (int i = 0; i < 4; ++i) {
      int r0 = bm + wm + i * 16 + (l4 << 2);
      #pragma unroll
      for (int q = 0; q < 4; ++q) {
        int row = r0 + q;
        if (row < M) C[(size_t)row * ldc + col] = f2b(fmaxf(acc[i][j][q] + bj, 0.0f));
      }
    }
  }
}

// ---- k_embhid: emb (K=512, pipelined) -> out_emb fp32 + embT LDS;
//      then 12 flat (hc,k0) steps for 3 hidden chunks -> hidden[Ncp][384] ----
__global__ __launch_bounds__(256) void k_embhid(
    const unsigned short* __restrict__ A2, const unsigned short* __restrict__ W2,
    const float* __restrict__ b2,
    const unsigned short* __restrict__ Whh, const float* __restrict__ bhh,
    float* __restrict__ out_emb, unsigned short* __restrict__ hidden, int M) {
  __shared__ __align__(16) unsigned short As[8192];  // dbuf
  __shared__ __align__(16) unsigned short Bs[8192];  // dbuf
  __shared__ __align__(16) unsigned short embT[16384];

  const int bm = blockIdx.x * 128;
  const int tid = threadIdx.x, lane = tid & 63, wave = tid >> 6;
  const int wm = (wave >> 1) << 6, wn = (wave & 1) << 6;
  const int l15 = lane & 15, l4 = lane >> 4;

  {  // emb: K=512, 16 pipelined steps
    const unsigned short* Abase = A2 + (size_t)bm * 512;
    f32x4 acc[4][4] = {};
    stage_tile(Abase, 512, As, wave, lane);
    stage_tile(W2, 512, Bs, wave, lane);
    __syncthreads();
    int cur = 0;
    for (int t = 0; t < 16; ++t) {
      if (t < 15) {
        stage_tile(Abase + (t + 1) * 32, 512, As + ((cur ^ 1) << 12), wave, lane);
        stage_tile(W2 + (t + 1) * 32, 512, Bs + ((cur ^ 1) << 12), wave, lane);
      }
      const unsigned short* Ac = As + (cur << 12);
      const unsigned short* Bc = Bs + (cur << 12);
      bf16x8 af[4], bfr[4];
      #pragma unroll
      for (int i = 0; i < 4; ++i) {
        af[i] = read_frag32(Ac, wm + i * 16 + l15, l4);
        bfr[i] = read_frag32(Bc, wn + i * 16 + l15, l4);
      }
      #pragma unroll
      for (int i = 0; i < 4; ++i)
        #pragma unroll
        for (int j = 0; j < 4; ++j)
          acc[i][j] = __builtin_amdgcn_mfma_f32_16x16x32_bf16(af[i], bfr[j], acc[i][j], 0, 0, 0);
      __syncthreads();
      cur ^= 1;
    }
    #pragma unroll
    for (int j = 0; j < 4; ++j) {
      int col = wn + j * 16 + l15;
      float bj = b2[col];
      #pragma unroll
      for (int i = 0; i < 4; ++i) {
        int r0 = wm + i * 16 + (l4 << 2);
        #pragma unroll
        for (int q = 0; q < 4; ++q) {
          float v = acc[i][j][q] + bj;
          int rl = r0 + q;
          if (bm + rl < M) out_emb[(size_t)(bm + rl) * 128 + col] = v;
          write_elem128(embT, rl, col, f2b(v));
        }
      }
    }
  }
  __syncthreads();

  // hidden: 12 flat steps (hc = s>>2, k0 = (s&3)*32), Whh staged dbuf
  f32x4 hacc[4][4] = {};
  stage_tile(Whh, 128, Bs, wave, lane);
  __syncthreads();
  int cur = 0;
  for (int s = 0; s < 12; ++s) {
    const int hc = s >> 2, tt = s & 3;
    if (s < 11) {
      const int s1 = s + 1;
      stage_tile(Whh + (size_t)(s1 >> 2) * 16384 + (s1 & 3) * 32, 128,
                 Bs + ((cur ^ 1) << 12), wave, lane);
    }
    const unsigned short* Bc = Bs + (cur << 12);
    bf16x8 af[4], bfr[4];
    const int kslot = tt * 4 + l4;
    #pragma unroll
    for (int i = 0; i < 4; ++i) {
      af[i] = read_frag128(embT, wm + i * 16 + l15, kslot);
      bfr[i] = read_frag32(Bc, wn + i * 16 + l15, l4);
    }
    #pragma unroll
    for (int i = 0; i < 4; ++i)
      #pragma unroll
      for (int j = 0; j < 4; ++j)
        hacc[i][j] = __builtin_amdgcn_mfma_f32_16x16x32_bf16(af[i], bfr[j], hacc[i][j], 0, 0, 0);
    if (tt == 3) {  // epilogue for this chunk
      #pragma unroll
      for (int j = 0; j < 4; ++j) {
        int col = wn + j * 16 + l15;
        float bj = bhh[hc * 128 + col];
        #pragma unroll
        for (int i = 0; i < 4; ++i) {
          int r0 = wm + i * 16 + (l4 << 2);
          #pragma unroll
          for (int q = 0; q < 4; ++q) {
            hidden[(size_t)(bm + r0 + q) * 384 + hc * 128 + col] =
                f2b(fmaxf(hacc[i][j][q] + bj, 0.0f));
            hacc[i][j][q] = 0.0f;
          }
        }
      }
    }
    __syncthreads();
    cur ^= 1;
  }
}

// ---- k_heads: per block one 128x128 head tile (cat/sku), or churn role ----
__global__ __launch_bounds__(256) void k_heads(
    const unsigned short* __restrict__ hidden,
    const unsigned short* __restrict__ Wcat, const float* __restrict__ bcat, int NCAT,
    int ncat_ch,
    const unsigned short* __restrict__ Wsku, const float* __restrict__ bsku, int NSKU,
    int nsku_ch,
    const float* __restrict__ wch2, const float* __restrict__ bch2,
    float* __restrict__ out_cat, float* __restrict__ out_sku,
    float* __restrict__ out_churn, int M) {
  __shared__ __align__(16) unsigned short Aw[16384];
  __shared__ __align__(16) unsigned short Bh[16384];

  const int nwg = gridDim.x, orig = blockIdx.x;
  const int q8 = nwg >> 3, r8 = nwg & 7;
  const int xcd = orig & 7, cidx = orig >> 3;
  const int wg = (xcd < r8 ? xcd * (q8 + 1) : r8 * (q8 + 1) + (xcd - r8) * q8) + cidx;

  const int nroles = ncat_ch + nsku_ch + 1;
  const int bt = wg / nroles;
  const int c = wg % nroles;
  const int bm = bt * 128;

  const int tid = threadIdx.x, lane = tid & 63, wave = tid >> 6;

  if (c == ncat_ch + nsku_ch) {
    // churn role: wave handles 32 rows, one dot each
    const float2 ww = *(const float2*)&wch2[lane * 2];
    const float bb = bch2[0];
    for (int r = wave * 32; r < wave * 32 + 32; ++r) {
      const int row = bm + r;
      if (row >= M) break;
      unsigned v = *(const unsigned*)&hidden[(size_t)row * 384 + lane * 2];
      float sum = waveReduceSum(b2f((unsigned short)(v & 0xFFFF)) * ww.x +
                                b2f((unsigned short)(v >> 16)) * ww.y);
      if (lane == 0) out_churn[row] = sigmoidf_(sum + bb);
    }
    return;
  }

  const unsigned short* Wh;
  const float* bh;
  float* oh;
  int Nh, cc, hoff;
  if (c < ncat_ch) { Wh = Wcat; bh = bcat; oh = out_cat; Nh = NCAT; cc = c; hoff = 128; }
  else { Wh = Wsku; bh = bsku; oh = out_sku; Nh = NSKU; cc = c - ncat_ch; hoff = 256; }

  const int wm = (wave >> 1) << 6, wn = (wave & 1) << 6;
  const int l15 = lane & 15, l4 = lane >> 4;

  stage_tile128(Wh + (size_t)cc * 128 * 128, 128, Aw, wave, lane);
  stage_tile128(hidden + (size_t)bm * 384 + hoff, 384, Bh, wave, lane);
  __syncthreads();

  f32x4 acc[4][4] = {};
  #pragma unroll
  for (int ks = 0; ks < 4; ++ks) {
    bf16x8 af[4], bfr[4];
    #pragma unroll
    for (int i = 0; i < 4; ++i) {
      af[i] = read_frag128(Aw, wm + i * 16 + l15, ks * 4 + l4);
      bfr[i] = read_frag128(Bh, wn + i * 16 + l15, ks * 4 + l4);
    }
    #pragma unroll
    for (int i = 0; i < 4; ++i)
      #pragma unroll
      for (int j = 0; j < 4; ++j)
        acc[i][j] = __builtin_amdgcn_mfma_f32_16x16x32_bf16(af[i], bfr[j], acc[i][j], 0, 0, 0);
  }

  #pragma unroll
  for (int i = 0; i < 4; ++i) {
    const int n0 = cc * 128 + wm + i * 16 + (l4 << 2);
    if (n0 < Nh) {  // Nh % 4 == 0 -> whole quad valid
      const float4 bv = *(const float4*)&bh[n0];
      #pragma unroll
      for (int j = 0; j < 4; ++j) {
        const int m = wn + j * 16 + l15;
        if (bm + m < M) {
          float4 ov;
          ov.x = sigmoidf_(acc[i][j][0] + bv.x);
          ov.y = sigmoidf_(acc[i][j][1] + bv.y);
          ov.z = sigmoidf_(acc[i][j][2] + bv.z);
          ov.w = sigmoidf_(acc[i][j][3] + bv.w);
          *(float4*)&oh[(size_t)(bm + m) * Nh + n0] = ov;
        }
      }
    }
  }
}

extern "C" void kernel_launch(void* const* d_in, const int* in_sizes, int n_in,
                              void* d_out, int out_size, void* d_ws, size_t ws_size,
                              hipStream_t stream) {
  const float* x_client = (const float*)d_in[0];
  const float* x_sku    = (const float*)d_in[1];
  const int* cs_src = (const int*)d_in[2];
  const int* cs_dst = (const int*)d_in[3];
  const int* sc_src = (const int*)d_in[4];
  const int* sc_dst = (const int*)d_in[5];
  const float* W1l_cs = (const float*)d_in[6];
  const float* b1_cs  = (const float*)d_in[7];
  const float* W1r_cs = (const float*)d_in[8];
  const float* W1l_sc = (const float*)d_in[9];
  const float* b1_sc  = (const float*)d_in[10];
  const float* W1r_sc = (const float*)d_in[11];
  const float* Wlin1_c = (const float*)d_in[12];
  const float* blin1_c = (const float*)d_in[13];
  const float* Wlin1_s = (const float*)d_in[14];
  const float* blin1_s = (const float*)d_in[15];
  const float* W2l_sc = (const float*)d_in[19];
  const float* b2_sc  = (const float*)d_in[20];
  const float* W2r_sc = (const float*)d_in[21];
  const float* Wlin2_c = (const float*)d_in[22];
  const float* blin2_c = (const float*)d_in[23];
  const float* Wch1 = (const float*)d_in[26];
  const float* bch1 = (const float*)d_in[27];
  const float* Wch2 = (const float*)d_in[28];
  const float* bch2 = (const float*)d_in[29];
  const float* Wcat1 = (const float*)d_in[30];
  const float* bcat1 = (const float*)d_in[31];
  const float* Wcat2 = (const float*)d_in[32];
  const float* bcat2 = (const float*)d_in[33];
  const float* Wsk1 = (const float*)d_in[34];
  const float* bsk1 = (const float*)d_in[35];
  const float* Wsk2 = (const float*)d_in[36];
  const float* bsk2 = (const float*)d_in[37];

  const int D = 128;
  const int Nc = in_sizes[0] / D;
  const int Ns = in_sizes[1] / D;
  const int E  = in_sizes[2];
  const int NCAT = in_sizes[33];
  const int NSKU = in_sizes[37];

  const int NTc = (Nc + 127) / 128;
  const int NTs = (Ns + 127) / 128;
  const int Ncp = NTc * 128;
  const int Nsp = NTs * 128;
  const int NCATp = ((NCAT + 127) / 128) * 128;
  const int NSKUp = ((NSKU + 127) / 128) * 128;
  const int ncat_ch = NCATp / 128, nsku_ch = NSKUp / 128;

  // ---- workspace layout ----
  char* wsb = (char*)d_ws;
  size_t o = 0;
  auto alloc = [&](size_t bytes) -> char* {
    char* p = wsb + o;
    o = (o + bytes + 255) & ~(size_t)255;
    return p;
  };
  unsigned short* concat_s = (unsigned short*)alloc((size_t)Nsp * 256 * 2);
  unsigned short* concat_c = (unsigned short*)alloc((size_t)Ncp * 256 * 2);
  unsigned short* h1_s     = (unsigned short*)alloc((size_t)Nsp * 256 * 2);
  unsigned short* big      = (unsigned short*)alloc((size_t)Ncp * 512 * 2);  // concat2
  unsigned short* hidden   = (unsigned short*)alloc((size_t)Ncp * 384 * 2);
  unsigned short* wc1s = (unsigned short*)alloc(256 * 256 * 2);
  float* bc1s = (float*)alloc(256 * 4);
  unsigned short* wc1c = (unsigned short*)alloc(256 * 256 * 2);
  float* bc1c = (float*)alloc(256 * 4);
  unsigned short* wc2c = (unsigned short*)alloc(128 * 512 * 2);
  float* bc2c = (float*)alloc(128 * 4);
  unsigned short* whh  = (unsigned short*)alloc(384 * 128 * 2);
  float* bhh  = (float*)alloc(384 * 4);
  unsigned short* wcat2p = (unsigned short*)alloc((size_t)NCATp * 128 * 2);
  unsigned short* wsk2p  = (unsigned short*)alloc((size_t)NSKUp * 128 * 2);
  int* off   = (int*)alloc((size_t)(Ns + Nc + 1) * 4);
  int* zbase = (int*)alloc((size_t)(2 * (Ns + Nc)) * 4);
  int* cnt = zbase;
  int* cur = zbase + (Ns + Nc);
  int* lst = (int*)alloc((size_t)(2 * E) * 4);
  int* partials = (int*)alloc(1024 * 4);

  float* out_churn = (float*)d_out;
  float* out_cat = out_churn + (size_t)Nc;
  float* out_sku = out_cat + (size_t)Nc * NCAT;
  float* out_emb = out_sku + (size_t)Nc * NSKU;

  hipMemsetAsync(zbase, 0, (size_t)(2 * (Ns + Nc)) * 4, stream);

  // 1. front: prep + l2norm + hist
  const int nl2 = (Nc + Ns + 3) / 4;
  const int nhist = (2 * E + 255) / 256;
  k_front<<<512 + nl2 + nhist, 256, 0, stream>>>(
      W1l_cs, W1r_cs, Wlin1_s, b1_cs, blin1_s,
      W1l_sc, W1r_sc, Wlin1_c, b1_sc, blin1_c,
      W2l_sc, W2r_sc, Wlin2_c, b2_sc, blin2_c,
      Wch1, bch1, Wcat1, bcat1, Wsk1, bsk1, Wcat2, Wsk2,
      wc1s, bc1s, wc1c, bc1c, wc2c, bc2c, whh, bhh, wcat2p, wsk2p,
      NCAT, NCATp, NSKU, NSKUp,
      x_client, x_sku, concat_c, concat_s, Nc, Ns, nl2,
      cs_dst, sc_dst, cnt, E);

  // 2-4. scan
  const int n_nodes = Ns + Nc;
  const int nb = (n_nodes + 1 + 2047) / 2048;
  k_scan1<<<nb, 256, 0, stream>>>(cnt, off, partials, n_nodes, n_nodes + 1);
  k_scan2<<<1, 256, 0, stream>>>(partials, nb);
  k_scan3<<<nb, 256, 0, stream>>>(off, partials, n_nodes + 1);

  // 5. scatter
  k_scatter_both<<<(2 * E + 255) / 256, 256, 0, stream>>>(
      cs_src, cs_dst, sc_src, sc_dst, off, cur, lst, E, Ns);

  // 6. layer-1 aggregation
  k_agg128_both<<<(n_nodes + 3) / 4, 256, 0, stream>>>(
      concat_c, concat_s, off, lst, concat_s, concat_c, Ns, Nc);

  // 7. layer-1 GEMMs (pipelined)
  k_gemm1_both<<<NTs * 2 + NTc * 2, 256, 0, stream>>>(
      concat_s, wc1s, bc1s, h1_s, Ns, NTs * 2,
      concat_c, wc1c, bc1c, big + 256, Nc);

  // 8. layer-2 aggregation (client destinations)
  k_agg_mean256<<<(Nc + 3) / 4, 256, 0, stream>>>(h1_s, off + Ns, lst, big, 512, Nc);

  // 9. emb + hidden (pipelined)
  k_embhid<<<NTc, 256, 0, stream>>>(big, wc2c, bc2c, whh, bhh, out_emb, hidden, Nc);

  // 10. heads + churn
  k_heads<<<NTc * (ncat_ch + nsku_ch + 1), 256, 0, stream>>>(
      hidden, wcat2p, bcat2, NCAT, ncat_ch, wsk2p, bsk2, NSKU, nsku_ch,
      Wch2, bch2, out_cat, out_sku, out_churn, Nc);
}